// Round 12
// baseline (306.821 us; speedup 1.0000x reference)
//
#include <hip/hip_runtime.h>

#define H 128
#define CH 4096
typedef unsigned short ushort_t;
typedef unsigned int uint_t;
typedef unsigned long long u64_t;
using s16x8 = __attribute__((ext_vector_type(8))) short;
using f32x4 = __attribute__((ext_vector_type(4))) float;
using h2 = __attribute__((ext_vector_type(2))) _Float16;

// ---------------------------------------------------------------- f16 helpers
__device__ __forceinline__ float dot2(uint_t a, uint_t b, float c) {
  return __builtin_amdgcn_fdot2(__builtin_bit_cast(h2, a), __builtin_bit_cast(h2, b), c, false);
}
__device__ __forceinline__ uint_t pkh(float a, float b) {
  return __builtin_bit_cast(uint_t, __builtin_amdgcn_cvt_pkrtz(a, b));
}
#define LO1 0x00003C00u  // (1.0h, 0)
#define HI1 0x3C000000u  // (0, 1.0h)

// ---------------------------------------------------------------- async global->LDS 16B
__device__ __forceinline__ void gload_lds16(const void* g, void* l) {
  __builtin_amdgcn_global_load_lds(
      (const __attribute__((address_space(1))) unsigned int*)(unsigned long long)g,
      (__attribute__((address_space(3))) unsigned int*)(unsigned int)(unsigned long long)l,
      16, 0, 0);
}

// ---------------------------------------------------------------- prologue (merged)
// [0,2048): fp32->f16 cvt; [2048,2560): wfrag x4; [2560,2560+nbc): bucket counts
__global__ __launch_bounds__(256) void prep_kernel(
    const float* __restrict__ xa, const float* __restrict__ xb,
    size_t n4a, size_t n4tot, uint2* __restrict__ xout,
    const float* __restrict__ Wl0, const float* __restrict__ Wr0,
    const float* __restrict__ Wl1, const float* __restrict__ Wr1,
    const float* __restrict__ Wl2, const float* __restrict__ Wr2,
    const float* __restrict__ Wl3, const float* __restrict__ Wr3,
    ushort_t* __restrict__ wdst,
    const int* __restrict__ src, const int* __restrict__ dst, const int* __restrict__ ls,
    int* __restrict__ bcnt, int E, int L, int nct, int NBt, int NBe) {
  const int b = blockIdx.x;
  const int tid = threadIdx.x;
  if (b < 2048) {
    size_t i = (size_t)b * 256 + tid;
    size_t s = 2048 * 256;
    for (; i < n4tot; i += s) {
      float4 v = (i < n4a) ? ((const float4*)xa)[i] : ((const float4*)xb)[i - n4a];
      uint2 r;
      r.x = pkh(v.x, v.y);
      r.y = pkh(v.z, v.w);
      xout[i] = r;
    }
  } else if (b < 2560) {
    int i = (b - 2048) * 256 + tid;  // 0..131071
    int w = i >> 15;
    int ii = i & 32767;
    int j = ii & 7;
    int lane = (ii >> 3) & 63;
    int nf = (ii >> 9) & 7;
    int ks = ii >> 12;
    int k = ks * 32 + (lane >> 4) * 8 + j;
    int nn = nf * 16 + (lane & 15);
    const float* Wl = (w == 0) ? Wl0 : (w == 1) ? Wl1 : (w == 2) ? Wl2 : Wl3;
    const float* Wr = (w == 0) ? Wr0 : (w == 1) ? Wr1 : (w == 2) ? Wr2 : Wr3;
    float v = (k < H) ? Wl[k * H + nn] : Wr[(k - H) * H + nn];
    wdst[i] = __builtin_bit_cast(ushort_t, (_Float16)v);
  } else {
    // bucket counts (bcnt pre-zeroed by hipMemsetAsync)
    __shared__ int hist[256];
    int cb = b - 2560;
    int stream, i0, n, base, shift;
    if (cb < nct) { stream = 0; i0 = cb * CH; n = E; base = 0; shift = 8; }
    else if (cb < 2 * nct) { stream = 1; i0 = (cb - nct) * CH; n = E; base = NBt; shift = 9; }
    else { stream = 2; i0 = (cb - 2 * nct) * CH; n = L; base = NBt + NBe; shift = 9; }
    const int* idx = (stream == 0) ? dst : (stream == 1) ? src : ls;
    const int i1 = min(n, i0 + CH);
    hist[tid] = 0;
    __syncthreads();
    for (int i = i0 + tid; i < i1; i += 256) atomicAdd(&hist[idx[i] >> shift], 1);
    __syncthreads();
    int h = hist[tid];
    if (h) atomicAdd(&bcnt[base + tid], h);
  }
}

// ---------------------------------------------------------------- tiny bucket scan (1 block)
__global__ void scan_buckets(const int* __restrict__ bcnt, int* __restrict__ boff,
                             int* __restrict__ cur, int n) {
  __shared__ int s[256];
  const int t = threadIdx.x;
  int carry = 0;
  for (int base = 0; base < n; base += 256) {
    int i = base + t;
    int v = (i < n) ? bcnt[i] : 0;
    s[t] = v;
    __syncthreads();
    for (int off = 1; off < 256; off <<= 1) {
      int x = (t >= off) ? s[t - off] : 0;
      __syncthreads();
      s[t] += x;
      __syncthreads();
    }
    if (i < n) { boff[i] = s[t] - v + carry; cur[i] = s[t] - v + carry; }
    __syncthreads();
    carry += s[255];
    __syncthreads();
  }
  if (t == 0) boff[n] = carry;
}

// ---------------------------------------------------------------- pass 1: radix bucket scatter
__global__ __launch_bounds__(256) void bucket_scatter(
    const int* __restrict__ src, const int* __restrict__ dst,
    const int* __restrict__ ls, const int* __restrict__ ld,
    int* __restrict__ cur, u64_t* __restrict__ recs,
    int E, int L, int nct, int NBt, int NBe) {
  __shared__ int hist[256];
  __shared__ int start[256];
  const int b = blockIdx.x;
  const int tid = threadIdx.x;
  int stream, i0, n, base;
  if (b < nct) { stream = 0; i0 = b * CH; n = E; base = 0; }
  else if (b < 2 * nct) { stream = 1; i0 = (b - nct) * CH; n = E; base = NBt; }
  else { stream = 2; i0 = (b - 2 * nct) * CH; n = L; base = NBt + NBe; }
  const int i1 = min(n, i0 + CH);

  hist[tid] = 0;
  __syncthreads();
  for (int i = i0 + tid; i < i1; i += 256) {
    int d = (stream == 0) ? dst[i] : (stream == 1) ? src[i] : ls[i];
    int bkt = (stream == 0) ? (d >> 8) : (d >> 9);
    atomicAdd(&hist[bkt], 1);
  }
  __syncthreads();
  int h = hist[tid];
  if (h) start[tid] = atomicAdd(&cur[base + tid], h);
  __syncthreads();
  for (int i = i0 + tid; i < i1; i += 256) {
    u64_t rec;
    int bkt;
    if (stream == 0) {
      int d = dst[i];
      rec = ((u64_t)d << 32) | (uint_t)src[i];
      bkt = d >> 8;
    } else if (stream == 1) {
      int d = src[i];
      rec = ((u64_t)d << 32) | (uint_t)dst[i];
      bkt = d >> 9;
    } else {
      int d = ls[i];
      rec = ((u64_t)d << 40) | ((u64_t)(uint_t)ld[i] << 20) | (uint_t)i;  // ls:24|ld:20|i:20
      bkt = d >> 9;
    }
    int pos = start[bkt] + atomicSub(&hist[bkt], 1) - 1;
    recs[pos] = rec;
  }
}

// ---------------------------------------------------------------- pass 2: in-bucket place
__global__ __launch_bounds__(256) void place_all(
    const u64_t* __restrict__ recs, const int* __restrict__ boff,
    int* __restrict__ off_t, int* __restrict__ off_e, int* __restrict__ off_l,
    int* __restrict__ adj_t, int* __restrict__ adj_e_m, long long* __restrict__ lpair_m,
    int n_t, int n_e, int NBt, int NBe) {
  __shared__ int sh[512];   // counts -> cursors
  __shared__ int tmp[256];
  const int b = blockIdx.x;
  const int tid = threadIdx.x;
  int stream, d0, d1, nmax;
  int* offg;
  if (b < NBt) { stream = 0; d0 = b << 8; d1 = min(n_t, d0 + 256); offg = off_t; nmax = n_t; }
  else if (b < NBt + NBe) { stream = 1; d0 = (b - NBt) << 9; d1 = min(n_e, d0 + 512); offg = off_e; nmax = n_e; }
  else { stream = 2; d0 = (b - NBt - NBe) << 9; d1 = min(n_e, d0 + 512); offg = off_l; nmax = n_e; }
  const int nn = d1 - d0;
  const int rs = boff[b], re = boff[b + 1];

  sh[tid] = 0;
  sh[tid + 256] = 0;
  __syncthreads();
  for (int i = rs + tid; i < re; i += 256) {
    u64_t rec = recs[i];
    int d = (stream == 2) ? (int)(rec >> 40) : (int)(rec >> 32);
    atomicAdd(&sh[d - d0], 1);
  }
  __syncthreads();
  int carry = 0;
  for (int c = 0; c < 2; ++c) {
    int idx = c * 256 + tid;
    int v = sh[idx];
    tmp[tid] = v;
    __syncthreads();
    for (int o = 1; o < 256; o <<= 1) {
      int x = (tid >= o) ? tmp[tid - o] : 0;
      __syncthreads();
      tmp[tid] += x;
      __syncthreads();
    }
    int excl = tmp[tid] - v + carry;
    if (idx < nn) {
      offg[d0 + idx] = rs + excl;
      sh[idx] = rs + excl;  // cursor
    }
    __syncthreads();
    carry += tmp[255];
    __syncthreads();
  }
  if (tid == 0) {
    bool last = (stream == 0 && b == NBt - 1) ||
                (stream == 1 && b == NBt + NBe - 1) ||
                (stream == 2 && b == NBt + NBe + NBe - 1);
    if (last) offg[nmax] = re;
  }
  __syncthreads();
  if (stream == 0) {
    for (int i = rs + tid; i < re; i += 256) {
      u64_t rec = recs[i];
      int d = (int)(rec >> 32);
      adj_t[atomicAdd(&sh[d - d0], 1)] = (int)rec;
    }
  } else if (stream == 1) {
    for (int i = rs + tid; i < re; i += 256) {
      u64_t rec = recs[i];
      int d = (int)(rec >> 32);
      adj_e_m[atomicAdd(&sh[d - d0], 1)] = (int)rec;
    }
  } else {
    for (int i = rs + tid; i < re; i += 256) {
      u64_t rec = recs[i];
      int d = (int)(rec >> 40);
      int ldv = (int)((rec >> 20) & 0xFFFFF);
      int li = (int)(rec & 0xFFFFF);
      lpair_m[atomicAdd(&sh[d - d0], 1)] = ((long long)ldv << 32) | (uint_t)li;
    }
  }
}

// ---------------------------------------------------------------- dual pull mean
// wave per node; 16-edge chunks: slot s loads int4 adj, 4 predicated row gathers.
__global__ void pull_mean_dual(
    const ushort_t* __restrict__ featA, const int* __restrict__ offA, const int* __restrict__ adjA,
    ushort_t* __restrict__ outA, int nA,
    const ushort_t* __restrict__ featB, const int* __restrict__ offB, const int* __restrict__ adjB,
    ushort_t* __restrict__ outB, int nB) {
  int gid = blockIdx.x * blockDim.x + threadIdx.x;
  int wave = gid >> 6;
  int lane = gid & 63;
  int slot = lane >> 4;
  int sl = lane & 15;
  int nw = (gridDim.x * blockDim.x) >> 6;
  for (int v = wave; v < nA + nB; v += nw) {
    const uint4* f;
    const int* off;
    const int* adj;
    uint4* o;
    int vv;
    if (v < nA) {
      f = (const uint4*)featA; off = offA; adj = adjA; o = (uint4*)outA; vv = v;
    } else {
      f = (const uint4*)featB; off = offB; adj = adjB; o = (uint4*)outB; vv = v - nA;
    }
    int s = off[vv], e = off[vv + 1];
    float acc[8];
#pragma unroll
    for (int c = 0; c < 8; ++c) acc[c] = 0.f;
    for (int i = s; i < e; i += 16) {
      int j0 = i + 4 * slot;
      if (j0 < e) {
        int4 a4 = *(const int4*)&adj[j0];  // ≤3-int over-read stays inside workspace
#pragma unroll
        for (int k = 0; k < 4; ++k) {
          if (j0 + k < e) {
            int idx = (k == 0) ? a4.x : (k == 1) ? a4.y : (k == 2) ? a4.z : a4.w;
            uint4 u = f[(size_t)idx * 16 + sl];
            acc[0] = dot2(u.x, LO1, acc[0]); acc[1] = dot2(u.x, HI1, acc[1]);
            acc[2] = dot2(u.y, LO1, acc[2]); acc[3] = dot2(u.y, HI1, acc[3]);
            acc[4] = dot2(u.z, LO1, acc[4]); acc[5] = dot2(u.z, HI1, acc[5]);
            acc[6] = dot2(u.w, LO1, acc[6]); acc[7] = dot2(u.w, HI1, acc[7]);
          }
        }
      }
    }
#pragma unroll
    for (int c = 0; c < 8; ++c) {
      acc[c] += __shfl_xor(acc[c], 16);
      acc[c] += __shfl_xor(acc[c], 32);
    }
    if (slot == 0) {
      float rd = 1.0f / fmaxf((float)(e - s), 1.0f);
      uint4 ov;
      ov.x = pkh(acc[0] * rd, acc[1] * rd);
      ov.y = pkh(acc[2] * rd, acc[3] * rd);
      ov.z = pkh(acc[4] * rd, acc[5] * rd);
      ov.w = pkh(acc[6] * rd, acc[7] * rd);
      o[(size_t)vv * 16 + sl] = ov;
    }
  }
}

// ---------------------------------------------------------------- dual MFMA GEMM (f16)
// (256,2): keeps B[8][4] (128 VGPR) register-resident (round-10 regression lesson)
template <bool RELU>
__global__ __launch_bounds__(256, 2) void gemm_mfma_dual(
    const ushort_t* __restrict__ aggA, const ushort_t* __restrict__ xdA,
    const ushort_t* __restrict__ wfA, const float* __restrict__ biasA,
    ushort_t* __restrict__ outA, int nA, int gA,
    const ushort_t* __restrict__ aggB, const ushort_t* __restrict__ xdB,
    const ushort_t* __restrict__ wfB, const float* __restrict__ biasB,
    ushort_t* __restrict__ outB, int nB) {
  __shared__ __align__(16) ushort_t sA[64 * 128];
  __shared__ __align__(16) ushort_t sX[64 * 128];
  const ushort_t *agg, *xd, *wfrag;
  const float* bias;
  ushort_t* outp;
  int n, b0, nbl;
  if ((int)blockIdx.x < gA) {
    agg = aggA; xd = xdA; wfrag = wfA; bias = biasA; outp = outA; n = nA;
    b0 = blockIdx.x; nbl = gA;
  } else {
    agg = aggB; xd = xdB; wfrag = wfB; bias = biasB; outp = outB; n = nB;
    b0 = blockIdx.x - gA; nbl = gridDim.x - gA;
  }
  const int t = threadIdx.x;
  const int lane = t & 63;
  const int wid = t >> 6;
  const int mrow = (wid >> 1) * 32;
  const int nhalf = (wid & 1) * 64;

  s16x8 B[8][4];
#pragma unroll
  for (int ks = 0; ks < 8; ++ks)
#pragma unroll
    for (int nfi = 0; nfi < 4; ++nfi)
      B[ks][nfi] = *(const s16x8*)(wfrag + (size_t)(((ks << 3) | ((nhalf >> 4) + nfi)) << 9) + (lane << 3));

  float bv[4];
#pragma unroll
  for (int nfi = 0; nfi < 4; ++nfi) bv[nfi] = bias[nhalf + nfi * 16 + (lane & 15)];

  const int lrow = lane >> 4;
  const int pbyte = (lane & 15) << 4;

  const int ntiles = (n + 63) >> 6;
  for (int tile = b0; tile < ntiles; tile += nbl) {
    const int row0 = tile << 6;
#pragma unroll
    for (int i = 0; i < 8; ++i) {
      int reg = (wid << 3) + i;
      int rr = ((reg & 15) << 2) + lrow;
      int row = row0 + rr;
      row = row < n ? row : n - 1;
      int pp = pbyte ^ ((rr & 7) << 4);
      const ushort_t* srcp = (reg < 16 ? agg : xd) + (size_t)row * H + (pp >> 1);
      ushort_t* ldst = (reg < 16 ? sA : sX) + ((reg & 15) << 9);
      gload_lds16(srcp, ldst);
    }
    __syncthreads();

    f32x4 acc[2][4];
#pragma unroll
    for (int mi = 0; mi < 2; ++mi)
#pragma unroll
      for (int nfi = 0; nfi < 4; ++nfi) {
        f32x4 c = {bv[nfi], bv[nfi], bv[nfi], bv[nfi]};
        acc[mi][nfi] = c;
      }

    const int rr0 = mrow + (lane & 15);
    const int rr1 = rr0 + 16;
    const int kx = (lane >> 4) << 4;
    const int sw = (rr0 & 7) << 4;
#pragma unroll
    for (int ks = 0; ks < 8; ++ks) {
      const ushort_t* base = (ks < 4) ? sA : sX;
      const int kb = (ks & 3) << 6;
      s16x8 a0 = *(const s16x8*)((const char*)base + rr0 * 256 + ((kb | kx) ^ sw));
      s16x8 a1 = *(const s16x8*)((const char*)base + rr1 * 256 + ((kb | kx) ^ sw));
#pragma unroll
      for (int nfi = 0; nfi < 4; ++nfi) {
        acc[0][nfi] = __builtin_amdgcn_mfma_f32_16x16x32_f16(a0, B[ks][nfi], acc[0][nfi], 0, 0, 0);
        acc[1][nfi] = __builtin_amdgcn_mfma_f32_16x16x32_f16(a1, B[ks][nfi], acc[1][nfi], 0, 0, 0);
      }
    }

#pragma unroll
    for (int mi = 0; mi < 2; ++mi) {
      int rbase = row0 + mrow + mi * 16 + ((lane >> 4) << 2);
#pragma unroll
      for (int r = 0; r < 4; ++r) {
        int row = rbase + r;
        if (row < n) {
#pragma unroll
          for (int nfi = 0; nfi < 4; ++nfi) {
            float v = acc[mi][nfi][r];
            if (RELU) v = fmaxf(v, 0.f);
            outp[(size_t)row * H + nhalf + nfi * 16 + (lane & 15)] =
                __builtin_bit_cast(ushort_t, (_Float16)v);
          }
        }
      }
    }
    __syncthreads();
  }
}

// ---------------------------------------------------------------- grouped edge dot (by EXPERT)
// wave per expert: z_e row in registers; gathers z_t rows (12.8MB table -> better L2).
__global__ void edge_dot_grouped(const ushort_t* __restrict__ zheld, const ushort_t* __restrict__ zgath,
                                 const int* __restrict__ loff, const long long* __restrict__ lpair,
                                 float* __restrict__ out, int nheld) {
  int gid = blockIdx.x * blockDim.x + threadIdx.x;
  int wave = gid >> 6;
  int lane = gid & 63;
  int slot = lane >> 4;
  int sl = lane & 15;
  int nw = (gridDim.x * blockDim.x) >> 6;
  const uint4* fh = (const uint4*)zheld;
  const uint4* fg = (const uint4*)zgath;
  for (int v = wave; v < nheld; v += nw) {
    int s = loff[v], e = loff[v + 1];
    if (s == e) continue;
    uint4 b = fh[(size_t)v * 16 + sl];
    for (int i = s; i < e; i += 16) {
      int j0 = i + 4 * slot;
      if (j0 < e) {
#pragma unroll
        for (int k = 0; k < 4; ++k) {
          int j = j0 + k;
          if (j < e) {
            long long q = lpair[j];
            int row = (int)(q >> 32);
            uint4 u = fg[(size_t)row * 16 + sl];
            float p = dot2(u.x, b.x, dot2(u.y, b.y, dot2(u.z, b.z, dot2(u.w, b.w, 0.f))));
            p += __shfl_xor(p, 1);
            p += __shfl_xor(p, 2);
            p += __shfl_xor(p, 4);
            p += __shfl_xor(p, 8);
            if (sl == 0) __builtin_nontemporal_store(p, &out[(int)q]);
          }
        }
      }
    }
  }
}

// ---------------------------------------------------------------- launch
extern "C" void kernel_launch(void* const* d_in, const int* in_sizes, int n_in,
                              void* d_out, int out_size, void* d_ws, size_t ws_size,
                              hipStream_t stream) {
  const float* x_e = (const float*)d_in[0];
  const float* x_t = (const float*)d_in[1];
  const int* src = (const int*)d_in[2];
  const int* dst = (const int*)d_in[3];
  const int* ls = (const int*)d_in[4];
  const int* ld = (const int*)d_in[5];
  const float* W1et_l = (const float*)d_in[6];
  const float* W1et_r = (const float*)d_in[7];
  const float* W1te_l = (const float*)d_in[8];
  const float* W1te_r = (const float*)d_in[9];
  const float* W2et_l = (const float*)d_in[10];
  const float* W2et_r = (const float*)d_in[11];
  const float* W2te_l = (const float*)d_in[12];
  const float* W2te_r = (const float*)d_in[13];
  const float* b1et = (const float*)d_in[14];
  const float* b1te = (const float*)d_in[15];
  const float* b2et = (const float*)d_in[16];
  const float* b2te = (const float*)d_in[17];

  const int n_e = in_sizes[0] / H;
  const int n_t = in_sizes[1] / H;
  const int E = in_sizes[2];
  const int L = in_sizes[4];
  float* out = (float*)d_out;

  const size_t fe = (size_t)n_e * H;
  const size_t ft = (size_t)n_t * H;
  ushort_t* us = (ushort_t*)d_ws;
  ushort_t* xb_e = us;               // fe
  ushort_t* xb_t = xb_e + fe;        // ft
  ushort_t* agg_e = xb_t + ft;       // fe  (layer2: z_expert in place)
  ushort_t* agg_t = agg_e + fe;      // ft  (… z_team in place)
  ushort_t* h_e = agg_t + ft;        // fe
  ushort_t* h_t = h_e + fe;          // ft
  ushort_t* wfrag = h_t + ft;        // 4*32768
  int* ib = (int*)(wfrag + 4 * 32768);

  const int Mt = n_t + 1, Me = n_e + 1;
  const int NBt = (n_t + 255) >> 8;   // team buckets (256)
  const int NBe = (n_e + 511) >> 9;   // expert buckets (512)
  const int NBtot = NBt + NBe + NBe;  // labels bucketed by EXPERT now

  int* off = ib;                   // Mt+Me+Me  ([off_t | off_e(+E) | off_l(+2E)])
  int* bcnt = off + Mt + Me + Me;  // NBtot+1
  int* boff = bcnt + NBtot + 1;    // NBtot+1
  int* cur = boff + NBtot + 1;     // NBtot
  int* adj_t = cur + NBtot;        // E
  int* adj_e = adj_t + E;          // E
  long long* lpair = (long long*)(((unsigned long long)(adj_e + E) + 7) & ~7ULL);  // L
  u64_t* recs = (u64_t*)(lpair + L);  // 2E+L

  int* off_t = off;
  int* off_e = off + Mt;            // values in [E, 2E]
  int* off_l = off + Mt + Me;       // values in [2E, 2E+L]
  int* adj_e_m = adj_e - E;
  long long* lpair_m = lpair - 2 * (size_t)E;

  const int nct = (E + CH - 1) / CH;
  const int ncl = (L + CH - 1) / CH;
  const int nbc = 2 * nct + ncl;

  const dim3 blk(256);

  // ---- zero bucket counters, then merged prologue (cvt + wfrag + bucket counts)
  hipMemsetAsync(bcnt, 0, (size_t)(NBtot + 1) * 4, stream);
  prep_kernel<<<2560 + nbc, blk, 0, stream>>>(
      x_e, x_t, fe / 4, (fe + ft) / 4, (uint2*)xb_e,
      W1et_l, W1et_r, W1te_l, W1te_r, W2et_l, W2et_r, W2te_l, W2te_r, wfrag,
      src, dst, ls, bcnt, E, L, nct, NBt, NBe);

  // ---- CSR build: tiny scan -> radix scatter -> in-bucket place
  scan_buckets<<<1, blk, 0, stream>>>(bcnt, boff, cur, NBtot);
  bucket_scatter<<<nbc, blk, 0, stream>>>(src, dst, ls, ld, cur, recs, E, L, nct, NBt, NBe);
  place_all<<<NBtot, blk, 0, stream>>>(recs, boff, off_t, off_e, off_l,
                                       adj_t, adj_e_m, lpair_m, n_t, n_e, NBt, NBe);

  const int gt = (n_t + 63) / 64, ge = (n_e + 63) / 64;
  const int gA = min(gt, 512), gB = min(ge, 512);
  const int npull = ((n_t + n_e) + 3) / 4;

  // ---- layer 1
  pull_mean_dual<<<npull, blk, 0, stream>>>(xb_e, off_t, adj_t, agg_t, n_t,
                                            xb_t, off_e, adj_e_m, agg_e, n_e);
  gemm_mfma_dual<true><<<gA + gB, blk, 0, stream>>>(
      agg_t, xb_t, wfrag + 0 * 32768, b1et, h_t, n_t, gA,
      agg_e, xb_e, wfrag + 1 * 32768, b1te, h_e, n_e);

  // ---- layer 2 (z written in place over agg)
  pull_mean_dual<<<npull, blk, 0, stream>>>(h_e, off_t, adj_t, agg_t, n_t,
                                            h_t, off_e, adj_e_m, agg_e, n_e);
  gemm_mfma_dual<false><<<gA + gB, blk, 0, stream>>>(
      agg_t, h_t, wfrag + 2 * 32768, b2et, agg_t, n_t, gA,
      agg_e, h_e, wfrag + 3 * 32768, b2te, agg_e, n_e);

  // ---- grouped edge dot readout (held = z_expert, gathered = z_team)
  edge_dot_grouped<<<(n_e + 3) / 4, blk, 0, stream>>>(agg_e, agg_t, off_l, lpair_m, out, n_e);
}

// Round 13
// 254.265 us; speedup vs baseline: 1.2067x; 1.2067x over previous
//
#include <hip/hip_runtime.h>

#define H 128
#define CH 4096
typedef unsigned short ushort_t;
typedef unsigned int uint_t;
typedef unsigned long long u64_t;
using s16x8 = __attribute__((ext_vector_type(8))) short;
using f32x4 = __attribute__((ext_vector_type(4))) float;
using h2 = __attribute__((ext_vector_type(2))) _Float16;

// ---------------------------------------------------------------- f16 helpers
__device__ __forceinline__ float dot2(uint_t a, uint_t b, float c) {
  return __builtin_amdgcn_fdot2(__builtin_bit_cast(h2, a), __builtin_bit_cast(h2, b), c, false);
}
__device__ __forceinline__ uint_t pkh(float a, float b) {
  return __builtin_bit_cast(uint_t, __builtin_amdgcn_cvt_pkrtz(a, b));
}

// ---------------------------------------------------------------- async global->LDS 16B
__device__ __forceinline__ void gload_lds16(const void* g, void* l) {
  __builtin_amdgcn_global_load_lds(
      (const __attribute__((address_space(1))) unsigned int*)(unsigned long long)g,
      (__attribute__((address_space(3))) unsigned int*)(unsigned int)(unsigned long long)l,
      16, 0, 0);
}

// ---------------------------------------------------------------- prologue (merged)
// [0,2048): fp32->f16 cvt; [2048,2560): wfrag x4; [2560,2560+nbc): bucket counts
__global__ __launch_bounds__(256) void prep_kernel(
    const float* __restrict__ xa, const float* __restrict__ xb,
    size_t n4a, size_t n4tot, uint2* __restrict__ xout,
    const float* __restrict__ Wl0, const float* __restrict__ Wr0,
    const float* __restrict__ Wl1, const float* __restrict__ Wr1,
    const float* __restrict__ Wl2, const float* __restrict__ Wr2,
    const float* __restrict__ Wl3, const float* __restrict__ Wr3,
    ushort_t* __restrict__ wdst,
    const int* __restrict__ src, const int* __restrict__ dst, const int* __restrict__ ld,
    int* __restrict__ bcnt, int E, int L, int nct, int NBt, int NBe) {
  const int b = blockIdx.x;
  const int tid = threadIdx.x;
  if (b < 2048) {
    size_t i = (size_t)b * 256 + tid;
    size_t s = 2048 * 256;
    for (; i < n4tot; i += s) {
      float4 v = (i < n4a) ? ((const float4*)xa)[i] : ((const float4*)xb)[i - n4a];
      uint2 r;
      r.x = pkh(v.x, v.y);
      r.y = pkh(v.z, v.w);
      xout[i] = r;
    }
  } else if (b < 2560) {
    int i = (b - 2048) * 256 + tid;  // 0..131071
    int w = i >> 15;
    int ii = i & 32767;
    int j = ii & 7;
    int lane = (ii >> 3) & 63;
    int nf = (ii >> 9) & 7;
    int ks = ii >> 12;
    int k = ks * 32 + (lane >> 4) * 8 + j;
    int nn = nf * 16 + (lane & 15);
    const float* Wl = (w == 0) ? Wl0 : (w == 1) ? Wl1 : (w == 2) ? Wl2 : Wl3;
    const float* Wr = (w == 0) ? Wr0 : (w == 1) ? Wr1 : (w == 2) ? Wr2 : Wr3;
    float v = (k < H) ? Wl[k * H + nn] : Wr[(k - H) * H + nn];
    wdst[i] = __builtin_bit_cast(ushort_t, (_Float16)v);
  } else {
    // bucket counts (bcnt pre-zeroed by hipMemsetAsync); labels bucketed by TEAM (ld)
    __shared__ int hist[256];
    int cb = b - 2560;
    int stream, i0, n, base, shift;
    if (cb < nct) { stream = 0; i0 = cb * CH; n = E; base = 0; shift = 8; }
    else if (cb < 2 * nct) { stream = 1; i0 = (cb - nct) * CH; n = E; base = NBt; shift = 9; }
    else { stream = 2; i0 = (cb - 2 * nct) * CH; n = L; base = NBt + NBe; shift = 8; }
    const int* idx = (stream == 0) ? dst : (stream == 1) ? src : ld;
    const int i1 = min(n, i0 + CH);
    hist[tid] = 0;
    __syncthreads();
    for (int i = i0 + tid; i < i1; i += 256) atomicAdd(&hist[idx[i] >> shift], 1);
    __syncthreads();
    int h = hist[tid];
    if (h) atomicAdd(&bcnt[base + tid], h);
  }
}

// ---------------------------------------------------------------- tiny bucket scan (1 block)
__global__ void scan_buckets(const int* __restrict__ bcnt, int* __restrict__ boff,
                             int* __restrict__ cur, int n) {
  __shared__ int s[256];
  const int t = threadIdx.x;
  int carry = 0;
  for (int base = 0; base < n; base += 256) {
    int i = base + t;
    int v = (i < n) ? bcnt[i] : 0;
    s[t] = v;
    __syncthreads();
    for (int off = 1; off < 256; off <<= 1) {
      int x = (t >= off) ? s[t - off] : 0;
      __syncthreads();
      s[t] += x;
      __syncthreads();
    }
    if (i < n) { boff[i] = s[t] - v + carry; cur[i] = s[t] - v + carry; }
    __syncthreads();
    carry += s[255];
    __syncthreads();
  }
  if (t == 0) boff[n] = carry;
}

// ---------------------------------------------------------------- pass 1: radix bucket scatter
__global__ __launch_bounds__(256) void bucket_scatter(
    const int* __restrict__ src, const int* __restrict__ dst,
    const int* __restrict__ ls, const int* __restrict__ ld,
    int* __restrict__ cur, u64_t* __restrict__ recs,
    int E, int L, int nct, int NBt, int NBe) {
  __shared__ int hist[256];
  __shared__ int start[256];
  const int b = blockIdx.x;
  const int tid = threadIdx.x;
  int stream, i0, n, base;
  if (b < nct) { stream = 0; i0 = b * CH; n = E; base = 0; }
  else if (b < 2 * nct) { stream = 1; i0 = (b - nct) * CH; n = E; base = NBt; }
  else { stream = 2; i0 = (b - 2 * nct) * CH; n = L; base = NBt + NBe; }
  const int i1 = min(n, i0 + CH);

  hist[tid] = 0;
  __syncthreads();
  for (int i = i0 + tid; i < i1; i += 256) {
    int d = (stream == 0) ? dst[i] : (stream == 1) ? src[i] : ld[i];
    int bkt = (stream == 1) ? (d >> 9) : (d >> 8);
    atomicAdd(&hist[bkt], 1);
  }
  __syncthreads();
  int h = hist[tid];
  if (h) start[tid] = atomicAdd(&cur[base + tid], h);
  __syncthreads();
  for (int i = i0 + tid; i < i1; i += 256) {
    u64_t rec;
    int bkt;
    if (stream == 0) {
      int d = dst[i];
      rec = ((u64_t)d << 32) | (uint_t)src[i];
      bkt = d >> 8;
    } else if (stream == 1) {
      int d = src[i];
      rec = ((u64_t)d << 32) | (uint_t)dst[i];
      bkt = d >> 9;
    } else {
      int d = ld[i];
      rec = ((u64_t)d << 40) | ((u64_t)(uint_t)ls[i] << 20) | (uint_t)i;  // d:24|ls:20|i:20
      bkt = d >> 8;
    }
    int pos = start[bkt] + atomicSub(&hist[bkt], 1) - 1;
    recs[pos] = rec;
  }
}

// ---------------------------------------------------------------- pass 2: in-bucket place
__global__ __launch_bounds__(256) void place_all(
    const u64_t* __restrict__ recs, const int* __restrict__ boff,
    int* __restrict__ off_t, int* __restrict__ off_e, int* __restrict__ off_l,
    int* __restrict__ adj_t, int* __restrict__ adj_e_m, long long* __restrict__ lpair_m,
    int n_t, int n_e, int NBt, int NBe, int NBl) {
  __shared__ int sh[512];   // counts -> cursors
  __shared__ int tmp[256];
  const int b = blockIdx.x;
  const int tid = threadIdx.x;
  int stream, d0, d1, nmax;
  int* offg;
  if (b < NBt) { stream = 0; d0 = b << 8; d1 = min(n_t, d0 + 256); offg = off_t; nmax = n_t; }
  else if (b < NBt + NBe) { stream = 1; d0 = (b - NBt) << 9; d1 = min(n_e, d0 + 512); offg = off_e; nmax = n_e; }
  else { stream = 2; d0 = (b - NBt - NBe) << 8; d1 = min(n_t, d0 + 256); offg = off_l; nmax = n_t; }
  const int nn = d1 - d0;
  const int rs = boff[b], re = boff[b + 1];

  sh[tid] = 0;
  sh[tid + 256] = 0;
  __syncthreads();
  for (int i = rs + tid; i < re; i += 256) {
    u64_t rec = recs[i];
    int d = (stream == 2) ? (int)(rec >> 40) : (int)(rec >> 32);
    atomicAdd(&sh[d - d0], 1);
  }
  __syncthreads();
  int carry = 0;
  for (int c = 0; c < 2; ++c) {
    int idx = c * 256 + tid;
    int v = sh[idx];
    tmp[tid] = v;
    __syncthreads();
    for (int o = 1; o < 256; o <<= 1) {
      int x = (tid >= o) ? tmp[tid - o] : 0;
      __syncthreads();
      tmp[tid] += x;
      __syncthreads();
    }
    int excl = tmp[tid] - v + carry;
    if (idx < nn) {
      offg[d0 + idx] = rs + excl;
      sh[idx] = rs + excl;  // cursor
    }
    __syncthreads();
    carry += tmp[255];
    __syncthreads();
  }
  if (tid == 0) {
    bool last = (stream == 0 && b == NBt - 1) ||
                (stream == 1 && b == NBt + NBe - 1) ||
                (stream == 2 && b == NBt + NBe + NBl - 1);
    if (last) offg[nmax] = re;
  }
  __syncthreads();
  if (stream == 0) {
    for (int i = rs + tid; i < re; i += 256) {
      u64_t rec = recs[i];
      int d = (int)(rec >> 32);
      adj_t[atomicAdd(&sh[d - d0], 1)] = (int)rec;
    }
  } else if (stream == 1) {
    for (int i = rs + tid; i < re; i += 256) {
      u64_t rec = recs[i];
      int d = (int)(rec >> 32);
      adj_e_m[atomicAdd(&sh[d - d0], 1)] = (int)rec;
    }
  } else {
    for (int i = rs + tid; i < re; i += 256) {
      u64_t rec = recs[i];
      int d = (int)(rec >> 40);
      int lsv = (int)((rec >> 20) & 0xFFFFF);
      int li = (int)(rec & 0xFFFFF);
      lpair_m[atomicAdd(&sh[d - d0], 1)] = ((long long)lsv << 32) | (uint_t)li;
    }
  }
}

// ---------------------------------------------------------------- dual pull mean (f16, 16-lane slots)
// round-11-proven: wave per node, 4 edge-slots x 16 lanes, uint4/lane, unroll 2.
__global__ void pull_mean_dual(
    const ushort_t* __restrict__ featA, const int* __restrict__ offA, const int* __restrict__ adjA,
    ushort_t* __restrict__ outA, int nA,
    const ushort_t* __restrict__ featB, const int* __restrict__ offB, const int* __restrict__ adjB,
    ushort_t* __restrict__ outB, int nB) {
  int gid = blockIdx.x * blockDim.x + threadIdx.x;
  int wave = gid >> 6;
  int lane = gid & 63;
  int slot = lane >> 4;
  int sl = lane & 15;
  int nw = (gridDim.x * blockDim.x) >> 6;
  for (int v = wave; v < nA + nB; v += nw) {
    const uint4* f;
    const int* off;
    const int* adj;
    uint4* o;
    int vv;
    if (v < nA) {
      f = (const uint4*)featA; off = offA; adj = adjA; o = (uint4*)outA; vv = v;
    } else {
      f = (const uint4*)featB; off = offB; adj = adjB; o = (uint4*)outB; vv = v - nA;
    }
    int s = off[vv], e = off[vv + 1];
    float acc[8];
#pragma unroll
    for (int c = 0; c < 8; ++c) acc[c] = 0.f;
#pragma unroll 2
    for (int i = s; i < e; i += 4) {
      int j = i + slot;
      bool val = j < e;
      int idx = adj[val ? j : i];
      uint4 u = f[(size_t)idx * 16 + sl];
      uint_t s_lo = val ? 0x00003C00u : 0u;  // (1.0h, 0)
      uint_t s_hi = val ? 0x3C000000u : 0u;  // (0, 1.0h)
      acc[0] = dot2(u.x, s_lo, acc[0]); acc[1] = dot2(u.x, s_hi, acc[1]);
      acc[2] = dot2(u.y, s_lo, acc[2]); acc[3] = dot2(u.y, s_hi, acc[3]);
      acc[4] = dot2(u.z, s_lo, acc[4]); acc[5] = dot2(u.z, s_hi, acc[5]);
      acc[6] = dot2(u.w, s_lo, acc[6]); acc[7] = dot2(u.w, s_hi, acc[7]);
    }
#pragma unroll
    for (int c = 0; c < 8; ++c) {
      acc[c] += __shfl_xor(acc[c], 16);
      acc[c] += __shfl_xor(acc[c], 32);
    }
    if (slot == 0) {
      float rd = 1.0f / fmaxf((float)(e - s), 1.0f);
      uint4 ov;
      ov.x = pkh(acc[0] * rd, acc[1] * rd);
      ov.y = pkh(acc[2] * rd, acc[3] * rd);
      ov.z = pkh(acc[4] * rd, acc[5] * rd);
      ov.w = pkh(acc[6] * rd, acc[7] * rd);
      o[(size_t)vv * 16 + sl] = ov;
    }
  }
}

// ---------------------------------------------------------------- dual MFMA GEMM (f16)
// (256,2): keeps B[8][4] (128 VGPR) register-resident (round-10 regression lesson)
template <bool RELU>
__global__ __launch_bounds__(256, 2) void gemm_mfma_dual(
    const ushort_t* __restrict__ aggA, const ushort_t* __restrict__ xdA,
    const ushort_t* __restrict__ wfA, const float* __restrict__ biasA,
    ushort_t* __restrict__ outA, int nA, int gA,
    const ushort_t* __restrict__ aggB, const ushort_t* __restrict__ xdB,
    const ushort_t* __restrict__ wfB, const float* __restrict__ biasB,
    ushort_t* __restrict__ outB, int nB) {
  __shared__ __align__(16) ushort_t sA[64 * 128];
  __shared__ __align__(16) ushort_t sX[64 * 128];
  const ushort_t *agg, *xd, *wfrag;
  const float* bias;
  ushort_t* outp;
  int n, b0, nbl;
  if ((int)blockIdx.x < gA) {
    agg = aggA; xd = xdA; wfrag = wfA; bias = biasA; outp = outA; n = nA;
    b0 = blockIdx.x; nbl = gA;
  } else {
    agg = aggB; xd = xdB; wfrag = wfB; bias = biasB; outp = outB; n = nB;
    b0 = blockIdx.x - gA; nbl = gridDim.x - gA;
  }
  const int t = threadIdx.x;
  const int lane = t & 63;
  const int wid = t >> 6;
  const int mrow = (wid >> 1) * 32;
  const int nhalf = (wid & 1) * 64;

  s16x8 B[8][4];
#pragma unroll
  for (int ks = 0; ks < 8; ++ks)
#pragma unroll
    for (int nfi = 0; nfi < 4; ++nfi)
      B[ks][nfi] = *(const s16x8*)(wfrag + (size_t)(((ks << 3) | ((nhalf >> 4) + nfi)) << 9) + (lane << 3));

  float bv[4];
#pragma unroll
  for (int nfi = 0; nfi < 4; ++nfi) bv[nfi] = bias[nhalf + nfi * 16 + (lane & 15)];

  const int lrow = lane >> 4;
  const int pbyte = (lane & 15) << 4;

  const int ntiles = (n + 63) >> 6;
  for (int tile = b0; tile < ntiles; tile += nbl) {
    const int row0 = tile << 6;
#pragma unroll
    for (int i = 0; i < 8; ++i) {
      int reg = (wid << 3) + i;
      int rr = ((reg & 15) << 2) + lrow;
      int row = row0 + rr;
      row = row < n ? row : n - 1;
      int pp = pbyte ^ ((rr & 7) << 4);
      const ushort_t* srcp = (reg < 16 ? agg : xd) + (size_t)row * H + (pp >> 1);
      ushort_t* ldst = (reg < 16 ? sA : sX) + ((reg & 15) << 9);
      gload_lds16(srcp, ldst);
    }
    __syncthreads();

    f32x4 acc[2][4];
#pragma unroll
    for (int mi = 0; mi < 2; ++mi)
#pragma unroll
      for (int nfi = 0; nfi < 4; ++nfi) {
        f32x4 c = {bv[nfi], bv[nfi], bv[nfi], bv[nfi]};
        acc[mi][nfi] = c;
      }

    const int rr0 = mrow + (lane & 15);
    const int rr1 = rr0 + 16;
    const int kx = (lane >> 4) << 4;
    const int sw = (rr0 & 7) << 4;
#pragma unroll
    for (int ks = 0; ks < 8; ++ks) {
      const ushort_t* base = (ks < 4) ? sA : sX;
      const int kb = (ks & 3) << 6;
      s16x8 a0 = *(const s16x8*)((const char*)base + rr0 * 256 + ((kb | kx) ^ sw));
      s16x8 a1 = *(const s16x8*)((const char*)base + rr1 * 256 + ((kb | kx) ^ sw));
#pragma unroll
      for (int nfi = 0; nfi < 4; ++nfi) {
        acc[0][nfi] = __builtin_amdgcn_mfma_f32_16x16x32_f16(a0, B[ks][nfi], acc[0][nfi], 0, 0, 0);
        acc[1][nfi] = __builtin_amdgcn_mfma_f32_16x16x32_f16(a1, B[ks][nfi], acc[1][nfi], 0, 0, 0);
      }
    }

#pragma unroll
    for (int mi = 0; mi < 2; ++mi) {
      int rbase = row0 + mrow + mi * 16 + ((lane >> 4) << 2);
#pragma unroll
      for (int r = 0; r < 4; ++r) {
        int row = rbase + r;
        if (row < n) {
#pragma unroll
          for (int nfi = 0; nfi < 4; ++nfi) {
            float v = acc[mi][nfi][r];
            if (RELU) v = fmaxf(v, 0.f);
            outp[(size_t)row * H + nhalf + nfi * 16 + (lane & 15)] =
                __builtin_bit_cast(ushort_t, (_Float16)v);
          }
        }
      }
    }
    __syncthreads();
  }
}

// ---------------------------------------------------------------- grouped edge dot (by team; round-11-proven)
__global__ void edge_dot_grouped(const ushort_t* __restrict__ ze, const ushort_t* __restrict__ zt,
                                 const int* __restrict__ loff, const long long* __restrict__ lpair,
                                 float* __restrict__ out, int n_t) {
  int gid = blockIdx.x * blockDim.x + threadIdx.x;
  int wave = gid >> 6;
  int lane = gid & 63;
  int slot = lane >> 4;
  int sl = lane & 15;
  int nw = (gridDim.x * blockDim.x) >> 6;
  const uint4* fz = (const uint4*)ze;
  const uint4* ft = (const uint4*)zt;
  for (int v = wave; v < n_t; v += nw) {
    int s = loff[v], e = loff[v + 1];
    if (s == e) continue;
    uint4 b = ft[(size_t)v * 16 + sl];
    for (int i = s; i < e; i += 4) {
      int j = i + slot;
      bool val = j < e;
      long long q = lpair[val ? j : i];
      int row = (int)(q >> 32);
      uint4 u = fz[(size_t)row * 16 + sl];
      float p = dot2(u.x, b.x, dot2(u.y, b.y, dot2(u.z, b.z, dot2(u.w, b.w, 0.f))));
      p += __shfl_xor(p, 1);
      p += __shfl_xor(p, 2);
      p += __shfl_xor(p, 4);
      p += __shfl_xor(p, 8);
      if (sl == 0 && val) __builtin_nontemporal_store(p, &out[(int)q]);
    }
  }
}

// ---------------------------------------------------------------- launch
extern "C" void kernel_launch(void* const* d_in, const int* in_sizes, int n_in,
                              void* d_out, int out_size, void* d_ws, size_t ws_size,
                              hipStream_t stream) {
  const float* x_e = (const float*)d_in[0];
  const float* x_t = (const float*)d_in[1];
  const int* src = (const int*)d_in[2];
  const int* dst = (const int*)d_in[3];
  const int* ls = (const int*)d_in[4];
  const int* ld = (const int*)d_in[5];
  const float* W1et_l = (const float*)d_in[6];
  const float* W1et_r = (const float*)d_in[7];
  const float* W1te_l = (const float*)d_in[8];
  const float* W1te_r = (const float*)d_in[9];
  const float* W2et_l = (const float*)d_in[10];
  const float* W2et_r = (const float*)d_in[11];
  const float* W2te_l = (const float*)d_in[12];
  const float* W2te_r = (const float*)d_in[13];
  const float* b1et = (const float*)d_in[14];
  const float* b1te = (const float*)d_in[15];
  const float* b2et = (const float*)d_in[16];
  const float* b2te = (const float*)d_in[17];

  const int n_e = in_sizes[0] / H;
  const int n_t = in_sizes[1] / H;
  const int E = in_sizes[2];
  const int L = in_sizes[4];
  float* out = (float*)d_out;

  const size_t fe = (size_t)n_e * H;
  const size_t ft = (size_t)n_t * H;
  ushort_t* us = (ushort_t*)d_ws;
  ushort_t* xb_e = us;               // fe
  ushort_t* xb_t = xb_e + fe;        // ft
  ushort_t* agg_e = xb_t + ft;       // fe  (layer2: z_expert in place)
  ushort_t* agg_t = agg_e + fe;      // ft  (… z_team in place)
  ushort_t* h_e = agg_t + ft;        // fe
  ushort_t* h_t = h_e + fe;          // ft
  ushort_t* wfrag = h_t + ft;        // 4*32768
  int* ib = (int*)(wfrag + 4 * 32768);

  const int Mt = n_t + 1, Me = n_e + 1, Ml = n_t + 1;
  const int NBt = (n_t + 255) >> 8;   // team buckets (256)
  const int NBe = (n_e + 511) >> 9;   // expert buckets (512)
  const int NBl = NBt;                // labels bucketed by team
  const int NBtot = NBt + NBe + NBl;

  int* off = ib;                   // Mt+Me+Ml  ([off_t | off_e(+E) | off_l(+2E)])
  int* bcnt = off + Mt + Me + Ml;  // NBtot+1
  int* boff = bcnt + NBtot + 1;    // NBtot+1
  int* cur = boff + NBtot + 1;     // NBtot
  int* adj_t = cur + NBtot;        // E
  int* adj_e = adj_t + E;          // E
  long long* lpair = (long long*)(((unsigned long long)(adj_e + E) + 7) & ~7ULL);  // L
  u64_t* recs = (u64_t*)(lpair + L);  // 2E+L

  int* off_t = off;
  int* off_e = off + Mt;            // values in [E, 2E]
  int* off_l = off + Mt + Me;       // values in [2E, 2E+L]
  int* adj_e_m = adj_e - E;
  long long* lpair_m = lpair - 2 * (size_t)E;

  const int nct = (E + CH - 1) / CH;
  const int ncl = (L + CH - 1) / CH;
  const int nbc = 2 * nct + ncl;

  const dim3 blk(256);

  // ---- zero bucket counters, then merged prologue (cvt + wfrag + bucket counts)
  hipMemsetAsync(bcnt, 0, (size_t)(NBtot + 1) * 4, stream);
  prep_kernel<<<2560 + nbc, blk, 0, stream>>>(
      x_e, x_t, fe / 4, (fe + ft) / 4, (uint2*)xb_e,
      W1et_l, W1et_r, W1te_l, W1te_r, W2et_l, W2et_r, W2te_l, W2te_r, wfrag,
      src, dst, ld, bcnt, E, L, nct, NBt, NBe);

  // ---- CSR build: tiny scan -> radix scatter -> in-bucket place
  scan_buckets<<<1, blk, 0, stream>>>(bcnt, boff, cur, NBtot);
  bucket_scatter<<<nbc, blk, 0, stream>>>(src, dst, ls, ld, cur, recs, E, L, nct, NBt, NBe);
  place_all<<<NBtot, blk, 0, stream>>>(recs, boff, off_t, off_e, off_l,
                                       adj_t, adj_e_m, lpair_m, n_t, n_e, NBt, NBe, NBl);

  const int gt = (n_t + 63) / 64, ge = (n_e + 63) / 64;
  const int gA = min(gt, 512), gB = min(ge, 512);
  const int npull = ((n_t + n_e) + 3) / 4;

  // ---- layer 1
  pull_mean_dual<<<npull, blk, 0, stream>>>(xb_e, off_t, adj_t, agg_t, n_t,
                                            xb_t, off_e, adj_e_m, agg_e, n_e);
  gemm_mfma_dual<true><<<gA + gB, blk, 0, stream>>>(
      agg_t, xb_t, wfrag + 0 * 32768, b1et, h_t, n_t, gA,
      agg_e, xb_e, wfrag + 1 * 32768, b1te, h_e, n_e);

  // ---- layer 2 (z written in place over agg)
  pull_mean_dual<<<npull, blk, 0, stream>>>(h_e, off_t, adj_t, agg_t, n_t,
                                            h_t, off_e, adj_e_m, agg_e, n_e);
  gemm_mfma_dual<false><<<gA + gB, blk, 0, stream>>>(
      agg_t, h_t, wfrag + 2 * 32768, b2et, agg_t, n_t, gA,
      agg_e, h_e, wfrag + 3 * 32768, b2te, agg_e, n_e);

  // ---- grouped edge dot readout (held = z_team, gathered = z_expert)
  edge_dot_grouped<<<(n_t + 3) / 4, blk, 0, stream>>>(agg_e, agg_t, off_l, lpair_m, out, n_t);
}

// Round 14
// 245.968 us; speedup vs baseline: 1.2474x; 1.0337x over previous
//
#include <hip/hip_runtime.h>

#define H 128
#define CH 4096
typedef unsigned short ushort_t;
typedef unsigned int uint_t;
typedef unsigned long long u64_t;
using s16x8 = __attribute__((ext_vector_type(8))) short;
using f32x4 = __attribute__((ext_vector_type(4))) float;
using h2 = __attribute__((ext_vector_type(2))) _Float16;

// ---------------------------------------------------------------- f16 helpers
__device__ __forceinline__ float dot2(uint_t a, uint_t b, float c) {
  return __builtin_amdgcn_fdot2(__builtin_bit_cast(h2, a), __builtin_bit_cast(h2, b), c, false);
}
__device__ __forceinline__ uint_t pkh(float a, float b) {
  return __builtin_bit_cast(uint_t, __builtin_amdgcn_cvt_pkrtz(a, b));
}
#define LO1 0x00003C00u  // (1.0h, 0)
#define HI1 0x3C000000u  // (0, 1.0h)

// ---------------------------------------------------------------- async global->LDS 16B
__device__ __forceinline__ void gload_lds16(const void* g, void* l) {
  __builtin_amdgcn_global_load_lds(
      (const __attribute__((address_space(1))) unsigned int*)(unsigned long long)g,
      (__attribute__((address_space(3))) unsigned int*)(unsigned int)(unsigned long long)l,
      16, 0, 0);
}

// ---------------------------------------------------------------- prologue (merged)
// [0,2048): fp32->f16 cvt; [2048,2560): wfrag x4; [2560,2560+nbc): bucket counts
__global__ __launch_bounds__(256) void prep_kernel(
    const float* __restrict__ xa, const float* __restrict__ xb,
    size_t n4a, size_t n4tot, uint2* __restrict__ xout,
    const float* __restrict__ Wl0, const float* __restrict__ Wr0,
    const float* __restrict__ Wl1, const float* __restrict__ Wr1,
    const float* __restrict__ Wl2, const float* __restrict__ Wr2,
    const float* __restrict__ Wl3, const float* __restrict__ Wr3,
    ushort_t* __restrict__ wdst,
    const int* __restrict__ src, const int* __restrict__ dst, const int* __restrict__ ld,
    int* __restrict__ bcnt, int E, int L, int nct, int NBt, int NBe) {
  const int b = blockIdx.x;
  const int tid = threadIdx.x;
  if (b < 2048) {
    size_t i = (size_t)b * 256 + tid;
    size_t s = 2048 * 256;
    for (; i < n4tot; i += s) {
      float4 v = (i < n4a) ? ((const float4*)xa)[i] : ((const float4*)xb)[i - n4a];
      uint2 r;
      r.x = pkh(v.x, v.y);
      r.y = pkh(v.z, v.w);
      xout[i] = r;
    }
  } else if (b < 2560) {
    int i = (b - 2048) * 256 + tid;  // 0..131071
    int w = i >> 15;
    int ii = i & 32767;
    int j = ii & 7;
    int lane = (ii >> 3) & 63;
    int nf = (ii >> 9) & 7;
    int ks = ii >> 12;
    int k = ks * 32 + (lane >> 4) * 8 + j;
    int nn = nf * 16 + (lane & 15);
    const float* Wl = (w == 0) ? Wl0 : (w == 1) ? Wl1 : (w == 2) ? Wl2 : Wl3;
    const float* Wr = (w == 0) ? Wr0 : (w == 1) ? Wr1 : (w == 2) ? Wr2 : Wr3;
    float v = (k < H) ? Wl[k * H + nn] : Wr[(k - H) * H + nn];
    wdst[i] = __builtin_bit_cast(ushort_t, (_Float16)v);
  } else {
    // bucket counts (bcnt pre-zeroed by hipMemsetAsync); labels bucketed by TEAM (ld)
    __shared__ int hist[256];
    int cb = b - 2560;
    int stream, i0, n, base, shift;
    if (cb < nct) { stream = 0; i0 = cb * CH; n = E; base = 0; shift = 8; }
    else if (cb < 2 * nct) { stream = 1; i0 = (cb - nct) * CH; n = E; base = NBt; shift = 9; }
    else { stream = 2; i0 = (cb - 2 * nct) * CH; n = L; base = NBt + NBe; shift = 8; }
    const int* idx = (stream == 0) ? dst : (stream == 1) ? src : ld;
    const int i1 = min(n, i0 + CH);
    hist[tid] = 0;
    __syncthreads();
    for (int i = i0 + tid; i < i1; i += 256) atomicAdd(&hist[idx[i] >> shift], 1);
    __syncthreads();
    int h = hist[tid];
    if (h) atomicAdd(&bcnt[base + tid], h);
  }
}

// ---------------------------------------------------------------- tiny bucket scan (1 block)
__global__ void scan_buckets(const int* __restrict__ bcnt, int* __restrict__ boff,
                             int* __restrict__ cur, int n) {
  __shared__ int s[256];
  const int t = threadIdx.x;
  int carry = 0;
  for (int base = 0; base < n; base += 256) {
    int i = base + t;
    int v = (i < n) ? bcnt[i] : 0;
    s[t] = v;
    __syncthreads();
    for (int off = 1; off < 256; off <<= 1) {
      int x = (t >= off) ? s[t - off] : 0;
      __syncthreads();
      s[t] += x;
      __syncthreads();
    }
    if (i < n) { boff[i] = s[t] - v + carry; cur[i] = s[t] - v + carry; }
    __syncthreads();
    carry += s[255];
    __syncthreads();
  }
  if (t == 0) boff[n] = carry;
}

// ---------------------------------------------------------------- pass 1: radix bucket scatter
__global__ __launch_bounds__(256) void bucket_scatter(
    const int* __restrict__ src, const int* __restrict__ dst,
    const int* __restrict__ ls, const int* __restrict__ ld,
    int* __restrict__ cur, u64_t* __restrict__ recs,
    int E, int L, int nct, int NBt, int NBe) {
  __shared__ int hist[256];
  __shared__ int start[256];
  const int b = blockIdx.x;
  const int tid = threadIdx.x;
  int stream, i0, n, base;
  if (b < nct) { stream = 0; i0 = b * CH; n = E; base = 0; }
  else if (b < 2 * nct) { stream = 1; i0 = (b - nct) * CH; n = E; base = NBt; }
  else { stream = 2; i0 = (b - 2 * nct) * CH; n = L; base = NBt + NBe; }
  const int i1 = min(n, i0 + CH);

  hist[tid] = 0;
  __syncthreads();
  for (int i = i0 + tid; i < i1; i += 256) {
    int d = (stream == 0) ? dst[i] : (stream == 1) ? src[i] : ld[i];
    int bkt = (stream == 1) ? (d >> 9) : (d >> 8);
    atomicAdd(&hist[bkt], 1);
  }
  __syncthreads();
  int h = hist[tid];
  if (h) start[tid] = atomicAdd(&cur[base + tid], h);
  __syncthreads();
  for (int i = i0 + tid; i < i1; i += 256) {
    u64_t rec;
    int bkt;
    if (stream == 0) {
      int d = dst[i];
      rec = ((u64_t)d << 32) | (uint_t)src[i];
      bkt = d >> 8;
    } else if (stream == 1) {
      int d = src[i];
      rec = ((u64_t)d << 32) | (uint_t)dst[i];
      bkt = d >> 9;
    } else {
      int d = ld[i];
      rec = ((u64_t)d << 40) | ((u64_t)(uint_t)ls[i] << 20) | (uint_t)i;  // d:24|ls:20|i:20
      bkt = d >> 8;
    }
    int pos = start[bkt] + atomicSub(&hist[bkt], 1) - 1;
    recs[pos] = rec;
  }
}

// ---------------------------------------------------------------- pass 2: in-bucket place
__global__ __launch_bounds__(256) void place_all(
    const u64_t* __restrict__ recs, const int* __restrict__ boff,
    int* __restrict__ off_t, int* __restrict__ off_e, int* __restrict__ off_l,
    int* __restrict__ adj_t, int* __restrict__ adj_e_m, long long* __restrict__ lpair_m,
    int n_t, int n_e, int NBt, int NBe, int NBl) {
  __shared__ int sh[512];   // counts -> cursors
  __shared__ int tmp[256];
  const int b = blockIdx.x;
  const int tid = threadIdx.x;
  int stream, d0, d1, nmax;
  int* offg;
  if (b < NBt) { stream = 0; d0 = b << 8; d1 = min(n_t, d0 + 256); offg = off_t; nmax = n_t; }
  else if (b < NBt + NBe) { stream = 1; d0 = (b - NBt) << 9; d1 = min(n_e, d0 + 512); offg = off_e; nmax = n_e; }
  else { stream = 2; d0 = (b - NBt - NBe) << 8; d1 = min(n_t, d0 + 256); offg = off_l; nmax = n_t; }
  const int nn = d1 - d0;
  const int rs = boff[b], re = boff[b + 1];

  sh[tid] = 0;
  sh[tid + 256] = 0;
  __syncthreads();
  for (int i = rs + tid; i < re; i += 256) {
    u64_t rec = recs[i];
    int d = (stream == 2) ? (int)(rec >> 40) : (int)(rec >> 32);
    atomicAdd(&sh[d - d0], 1);
  }
  __syncthreads();
  int carry = 0;
  for (int c = 0; c < 2; ++c) {
    int idx = c * 256 + tid;
    int v = sh[idx];
    tmp[tid] = v;
    __syncthreads();
    for (int o = 1; o < 256; o <<= 1) {
      int x = (tid >= o) ? tmp[tid - o] : 0;
      __syncthreads();
      tmp[tid] += x;
      __syncthreads();
    }
    int excl = tmp[tid] - v + carry;
    if (idx < nn) {
      offg[d0 + idx] = rs + excl;
      sh[idx] = rs + excl;  // cursor
    }
    __syncthreads();
    carry += tmp[255];
    __syncthreads();
  }
  if (tid == 0) {
    bool last = (stream == 0 && b == NBt - 1) ||
                (stream == 1 && b == NBt + NBe - 1) ||
                (stream == 2 && b == NBt + NBe + NBl - 1);
    if (last) offg[nmax] = re;
  }
  __syncthreads();
  if (stream == 0) {
    for (int i = rs + tid; i < re; i += 256) {
      u64_t rec = recs[i];
      int d = (int)(rec >> 32);
      adj_t[atomicAdd(&sh[d - d0], 1)] = (int)rec;
    }
  } else if (stream == 1) {
    for (int i = rs + tid; i < re; i += 256) {
      u64_t rec = recs[i];
      int d = (int)(rec >> 32);
      adj_e_m[atomicAdd(&sh[d - d0], 1)] = (int)rec;
    }
  } else {
    for (int i = rs + tid; i < re; i += 256) {
      u64_t rec = recs[i];
      int d = (int)(rec >> 40);
      int lsv = (int)((rec >> 20) & 0xFFFFF);
      int li = (int)(rec & 0xFFFFF);
      lpair_m[atomicAdd(&sh[d - d0], 1)] = ((long long)lsv << 32) | (uint_t)li;
    }
  }
}

// ---------------------------------------------------------------- dual pull mean (slot-per-node)
// wave = 4 independent nodes; each 16-lane slot walks its node's adjacency serially.
// No cross-slot reduce, no duplicate tail gathers.
__global__ void pull_mean_dual(
    const ushort_t* __restrict__ featA, const int* __restrict__ offA, const int* __restrict__ adjA,
    ushort_t* __restrict__ outA, int nA,
    const ushort_t* __restrict__ featB, const int* __restrict__ offB, const int* __restrict__ adjB,
    ushort_t* __restrict__ outB, int nB) {
  int gid = blockIdx.x * blockDim.x + threadIdx.x;
  int wave = gid >> 6;
  int lane = gid & 63;
  int slot = lane >> 4;
  int sl = lane & 15;
  int nw = (gridDim.x * blockDim.x) >> 6;
  const int N = nA + nB;
  for (int v0 = wave * 4; v0 < N; v0 += nw * 4) {
    int v = v0 + slot;
    bool valid = v < N;
    const uint4* f;
    const int* off;
    const int* adj;
    uint4* o;
    int vv;
    if (v < nA) {
      f = (const uint4*)featA; off = offA; adj = adjA; o = (uint4*)outA; vv = v;
    } else {
      f = (const uint4*)featB; off = offB; adj = adjB; o = (uint4*)outB;
      vv = valid ? v - nA : 0;
    }
    int s = 0, e = 0;
    if (valid) { s = off[vv]; e = off[vv + 1]; }
    float acc[8];
#pragma unroll
    for (int c = 0; c < 8; ++c) acc[c] = 0.f;
    int i = s;
    // unroll-2: keep 2 rows in flight per slot
    for (; i + 2 <= e; i += 2) {
      int i0 = adj[i], i1 = adj[i + 1];
      uint4 u0 = f[(size_t)i0 * 16 + sl];
      uint4 u1 = f[(size_t)i1 * 16 + sl];
      acc[0] = dot2(u0.x, LO1, acc[0]); acc[1] = dot2(u0.x, HI1, acc[1]);
      acc[2] = dot2(u0.y, LO1, acc[2]); acc[3] = dot2(u0.y, HI1, acc[3]);
      acc[4] = dot2(u0.z, LO1, acc[4]); acc[5] = dot2(u0.z, HI1, acc[5]);
      acc[6] = dot2(u0.w, LO1, acc[6]); acc[7] = dot2(u0.w, HI1, acc[7]);
      acc[0] = dot2(u1.x, LO1, acc[0]); acc[1] = dot2(u1.x, HI1, acc[1]);
      acc[2] = dot2(u1.y, LO1, acc[2]); acc[3] = dot2(u1.y, HI1, acc[3]);
      acc[4] = dot2(u1.z, LO1, acc[4]); acc[5] = dot2(u1.z, HI1, acc[5]);
      acc[6] = dot2(u1.w, LO1, acc[6]); acc[7] = dot2(u1.w, HI1, acc[7]);
    }
    if (i < e) {
      uint4 u = f[(size_t)adj[i] * 16 + sl];
      acc[0] = dot2(u.x, LO1, acc[0]); acc[1] = dot2(u.x, HI1, acc[1]);
      acc[2] = dot2(u.y, LO1, acc[2]); acc[3] = dot2(u.y, HI1, acc[3]);
      acc[4] = dot2(u.z, LO1, acc[4]); acc[5] = dot2(u.z, HI1, acc[5]);
      acc[6] = dot2(u.w, LO1, acc[6]); acc[7] = dot2(u.w, HI1, acc[7]);
    }
    if (valid) {
      float rd = 1.0f / fmaxf((float)(e - s), 1.0f);
      uint4 ov;
      ov.x = pkh(acc[0] * rd, acc[1] * rd);
      ov.y = pkh(acc[2] * rd, acc[3] * rd);
      ov.z = pkh(acc[4] * rd, acc[5] * rd);
      ov.w = pkh(acc[6] * rd, acc[7] * rd);
      o[(size_t)vv * 16 + sl] = ov;
    }
  }
}

// ---------------------------------------------------------------- dual MFMA GEMM (f16)
// (256,2): keeps B[8][4] (128 VGPR) register-resident (round-10 regression lesson)
template <bool RELU>
__global__ __launch_bounds__(256, 2) void gemm_mfma_dual(
    const ushort_t* __restrict__ aggA, const ushort_t* __restrict__ xdA,
    const ushort_t* __restrict__ wfA, const float* __restrict__ biasA,
    ushort_t* __restrict__ outA, int nA, int gA,
    const ushort_t* __restrict__ aggB, const ushort_t* __restrict__ xdB,
    const ushort_t* __restrict__ wfB, const float* __restrict__ biasB,
    ushort_t* __restrict__ outB, int nB) {
  __shared__ __align__(16) ushort_t sA[64 * 128];
  __shared__ __align__(16) ushort_t sX[64 * 128];
  const ushort_t *agg, *xd, *wfrag;
  const float* bias;
  ushort_t* outp;
  int n, b0, nbl;
  if ((int)blockIdx.x < gA) {
    agg = aggA; xd = xdA; wfrag = wfA; bias = biasA; outp = outA; n = nA;
    b0 = blockIdx.x; nbl = gA;
  } else {
    agg = aggB; xd = xdB; wfrag = wfB; bias = biasB; outp = outB; n = nB;
    b0 = blockIdx.x - gA; nbl = gridDim.x - gA;
  }
  const int t = threadIdx.x;
  const int lane = t & 63;
  const int wid = t >> 6;
  const int mrow = (wid >> 1) * 32;
  const int nhalf = (wid & 1) * 64;

  s16x8 B[8][4];
#pragma unroll
  for (int ks = 0; ks < 8; ++ks)
#pragma unroll
    for (int nfi = 0; nfi < 4; ++nfi)
      B[ks][nfi] = *(const s16x8*)(wfrag + (size_t)(((ks << 3) | ((nhalf >> 4) + nfi)) << 9) + (lane << 3));

  float bv[4];
#pragma unroll
  for (int nfi = 0; nfi < 4; ++nfi) bv[nfi] = bias[nhalf + nfi * 16 + (lane & 15)];

  const int lrow = lane >> 4;
  const int pbyte = (lane & 15) << 4;

  const int ntiles = (n + 63) >> 6;
  for (int tile = b0; tile < ntiles; tile += nbl) {
    const int row0 = tile << 6;
#pragma unroll
    for (int i = 0; i < 8; ++i) {
      int reg = (wid << 3) + i;
      int rr = ((reg & 15) << 2) + lrow;
      int row = row0 + rr;
      row = row < n ? row : n - 1;
      int pp = pbyte ^ ((rr & 7) << 4);
      const ushort_t* srcp = (reg < 16 ? agg : xd) + (size_t)row * H + (pp >> 1);
      ushort_t* ldst = (reg < 16 ? sA : sX) + ((reg & 15) << 9);
      gload_lds16(srcp, ldst);
    }
    __syncthreads();

    f32x4 acc[2][4];
#pragma unroll
    for (int mi = 0; mi < 2; ++mi)
#pragma unroll
      for (int nfi = 0; nfi < 4; ++nfi) {
        f32x4 c = {bv[nfi], bv[nfi], bv[nfi], bv[nfi]};
        acc[mi][nfi] = c;
      }

    const int rr0 = mrow + (lane & 15);
    const int rr1 = rr0 + 16;
    const int kx = (lane >> 4) << 4;
    const int sw = (rr0 & 7) << 4;
#pragma unroll
    for (int ks = 0; ks < 8; ++ks) {
      const ushort_t* base = (ks < 4) ? sA : sX;
      const int kb = (ks & 3) << 6;
      s16x8 a0 = *(const s16x8*)((const char*)base + rr0 * 256 + ((kb | kx) ^ sw));
      s16x8 a1 = *(const s16x8*)((const char*)base + rr1 * 256 + ((kb | kx) ^ sw));
#pragma unroll
      for (int nfi = 0; nfi < 4; ++nfi) {
        acc[0][nfi] = __builtin_amdgcn_mfma_f32_16x16x32_f16(a0, B[ks][nfi], acc[0][nfi], 0, 0, 0);
        acc[1][nfi] = __builtin_amdgcn_mfma_f32_16x16x32_f16(a1, B[ks][nfi], acc[1][nfi], 0, 0, 0);
      }
    }

#pragma unroll
    for (int mi = 0; mi < 2; ++mi) {
      int rbase = row0 + mrow + mi * 16 + ((lane >> 4) << 2);
#pragma unroll
      for (int r = 0; r < 4; ++r) {
        int row = rbase + r;
        if (row < n) {
#pragma unroll
          for (int nfi = 0; nfi < 4; ++nfi) {
            float v = acc[mi][nfi][r];
            if (RELU) v = fmaxf(v, 0.f);
            outp[(size_t)row * H + nhalf + nfi * 16 + (lane & 15)] =
                __builtin_bit_cast(ushort_t, (_Float16)v);
          }
        }
      }
    }
    __syncthreads();
  }
}

// ---------------------------------------------------------------- grouped edge dot (by team; round-11-proven)
__global__ void edge_dot_grouped(const ushort_t* __restrict__ ze, const ushort_t* __restrict__ zt,
                                 const int* __restrict__ loff, const long long* __restrict__ lpair,
                                 float* __restrict__ out, int n_t) {
  int gid = blockIdx.x * blockDim.x + threadIdx.x;
  int wave = gid >> 6;
  int lane = gid & 63;
  int slot = lane >> 4;
  int sl = lane & 15;
  int nw = (gridDim.x * blockDim.x) >> 6;
  const uint4* fz = (const uint4*)ze;
  const uint4* ft = (const uint4*)zt;
  for (int v = wave; v < n_t; v += nw) {
    int s = loff[v], e = loff[v + 1];
    if (s == e) continue;
    uint4 b = ft[(size_t)v * 16 + sl];
    for (int i = s; i < e; i += 4) {
      int j = i + slot;
      bool val = j < e;
      long long q = lpair[val ? j : i];
      int row = (int)(q >> 32);
      uint4 u = fz[(size_t)row * 16 + sl];
      float p = dot2(u.x, b.x, dot2(u.y, b.y, dot2(u.z, b.z, dot2(u.w, b.w, 0.f))));
      p += __shfl_xor(p, 1);
      p += __shfl_xor(p, 2);
      p += __shfl_xor(p, 4);
      p += __shfl_xor(p, 8);
      if (sl == 0 && val) __builtin_nontemporal_store(p, &out[(int)q]);
    }
  }
}

// ---------------------------------------------------------------- launch
extern "C" void kernel_launch(void* const* d_in, const int* in_sizes, int n_in,
                              void* d_out, int out_size, void* d_ws, size_t ws_size,
                              hipStream_t stream) {
  const float* x_e = (const float*)d_in[0];
  const float* x_t = (const float*)d_in[1];
  const int* src = (const int*)d_in[2];
  const int* dst = (const int*)d_in[3];
  const int* ls = (const int*)d_in[4];
  const int* ld = (const int*)d_in[5];
  const float* W1et_l = (const float*)d_in[6];
  const float* W1et_r = (const float*)d_in[7];
  const float* W1te_l = (const float*)d_in[8];
  const float* W1te_r = (const float*)d_in[9];
  const float* W2et_l = (const float*)d_in[10];
  const float* W2et_r = (const float*)d_in[11];
  const float* W2te_l = (const float*)d_in[12];
  const float* W2te_r = (const float*)d_in[13];
  const float* b1et = (const float*)d_in[14];
  const float* b1te = (const float*)d_in[15];
  const float* b2et = (const float*)d_in[16];
  const float* b2te = (const float*)d_in[17];

  const int n_e = in_sizes[0] / H;
  const int n_t = in_sizes[1] / H;
  const int E = in_sizes[2];
  const int L = in_sizes[4];
  float* out = (float*)d_out;

  const size_t fe = (size_t)n_e * H;
  const size_t ft = (size_t)n_t * H;
  ushort_t* us = (ushort_t*)d_ws;
  ushort_t* xb_e = us;               // fe
  ushort_t* xb_t = xb_e + fe;        // ft
  ushort_t* agg_e = xb_t + ft;       // fe  (layer2: z_expert in place)
  ushort_t* agg_t = agg_e + fe;      // ft  (… z_team in place)
  ushort_t* h_e = agg_t + ft;        // fe
  ushort_t* h_t = h_e + fe;          // ft
  ushort_t* wfrag = h_t + ft;        // 4*32768
  int* ib = (int*)(wfrag + 4 * 32768);

  const int Mt = n_t + 1, Me = n_e + 1, Ml = n_t + 1;
  const int NBt = (n_t + 255) >> 8;   // team buckets (256)
  const int NBe = (n_e + 511) >> 9;   // expert buckets (512)
  const int NBl = NBt;                // labels bucketed by team
  const int NBtot = NBt + NBe + NBl;

  int* off = ib;                   // Mt+Me+Ml  ([off_t | off_e(+E) | off_l(+2E)])
  int* bcnt = off + Mt + Me + Ml;  // NBtot+1
  int* boff = bcnt + NBtot + 1;    // NBtot+1
  int* cur = boff + NBtot + 1;     // NBtot
  int* adj_t = cur + NBtot;        // E
  int* adj_e = adj_t + E;          // E
  long long* lpair = (long long*)(((unsigned long long)(adj_e + E) + 7) & ~7ULL);  // L
  u64_t* recs = (u64_t*)(lpair + L);  // 2E+L

  int* off_t = off;
  int* off_e = off + Mt;            // values in [E, 2E]
  int* off_l = off + Mt + Me;       // values in [2E, 2E+L]
  int* adj_e_m = adj_e - E;
  long long* lpair_m = lpair - 2 * (size_t)E;

  const int nct = (E + CH - 1) / CH;
  const int ncl = (L + CH - 1) / CH;
  const int nbc = 2 * nct + ncl;

  const dim3 blk(256);

  // ---- zero bucket counters, then merged prologue (cvt + wfrag + bucket counts)
  hipMemsetAsync(bcnt, 0, (size_t)(NBtot + 1) * 4, stream);
  prep_kernel<<<2560 + nbc, blk, 0, stream>>>(
      x_e, x_t, fe / 4, (fe + ft) / 4, (uint2*)xb_e,
      W1et_l, W1et_r, W1te_l, W1te_r, W2et_l, W2et_r, W2te_l, W2te_r, wfrag,
      src, dst, ld, bcnt, E, L, nct, NBt, NBe);

  // ---- CSR build: tiny scan -> radix scatter -> in-bucket place
  scan_buckets<<<1, blk, 0, stream>>>(bcnt, boff, cur, NBtot);
  bucket_scatter<<<nbc, blk, 0, stream>>>(src, dst, ls, ld, cur, recs, E, L, nct, NBt, NBe);
  place_all<<<NBtot, blk, 0, stream>>>(recs, boff, off_t, off_e, off_l,
                                       adj_t, adj_e_m, lpair_m, n_t, n_e, NBt, NBe, NBl);

  const int gt = (n_t + 63) / 64, ge = (n_e + 63) / 64;
  const int gA = min(gt, 512), gB = min(ge, 512);
  const int npull = ((n_t + n_e) + 3) / 4;

  // ---- layer 1
  pull_mean_dual<<<npull, blk, 0, stream>>>(xb_e, off_t, adj_t, agg_t, n_t,
                                            xb_t, off_e, adj_e_m, agg_e, n_e);
  gemm_mfma_dual<true><<<gA + gB, blk, 0, stream>>>(
      agg_t, xb_t, wfrag + 0 * 32768, b1et, h_t, n_t, gA,
      agg_e, xb_e, wfrag + 1 * 32768, b1te, h_e, n_e);

  // ---- layer 2 (z written in place over agg)
  pull_mean_dual<<<npull, blk, 0, stream>>>(h_e, off_t, adj_t, agg_t, n_t,
                                            h_t, off_e, adj_e_m, agg_e, n_e);
  gemm_mfma_dual<false><<<gA + gB, blk, 0, stream>>>(
      agg_t, h_t, wfrag + 2 * 32768, b2et, agg_t, n_t, gA,
      agg_e, h_e, wfrag + 3 * 32768, b2te, agg_e, n_e);

  // ---- grouped edge dot readout (held = z_team, gathered = z_expert)
  edge_dot_grouped<<<(n_t + 3) / 4, blk, 0, stream>>>(agg_e, agg_t, off_l, lpair_m, out, n_t);
}

// Round 15
// 242.549 us; speedup vs baseline: 1.2650x; 1.0141x over previous
//
#include <hip/hip_runtime.h>

#define H 128
#define CH 4096
typedef unsigned short ushort_t;
typedef unsigned int uint_t;
typedef unsigned long long u64_t;
using s16x8 = __attribute__((ext_vector_type(8))) short;
using f32x4 = __attribute__((ext_vector_type(4))) float;
using h2 = __attribute__((ext_vector_type(2))) _Float16;

// ---------------------------------------------------------------- f16 helpers
__device__ __forceinline__ float dot2(uint_t a, uint_t b, float c) {
  return __builtin_amdgcn_fdot2(__builtin_bit_cast(h2, a), __builtin_bit_cast(h2, b), c, false);
}
__device__ __forceinline__ uint_t pkh(float a, float b) {
  return __builtin_bit_cast(uint_t, __builtin_amdgcn_cvt_pkrtz(a, b));
}
#define LO1 0x00003C00u  // (1.0h, 0)
#define HI1 0x3C000000u  // (0, 1.0h)

// ---------------------------------------------------------------- async global->LDS 16B
__device__ __forceinline__ void gload_lds16(const void* g, void* l) {
  __builtin_amdgcn_global_load_lds(
      (const __attribute__((address_space(1))) unsigned int*)(unsigned long long)g,
      (__attribute__((address_space(3))) unsigned int*)(unsigned int)(unsigned long long)l,
      16, 0, 0);
}

// ---------------------------------------------------------------- prologue (merged)
// [0,2048): fp32->f16 cvt; [2048,2560): wfrag x4; [2560,2560+nbc): bucket counts
__global__ __launch_bounds__(256) void prep_kernel(
    const float* __restrict__ xa, const float* __restrict__ xb,
    size_t n4a, size_t n4tot, uint2* __restrict__ xout,
    const float* __restrict__ Wl0, const float* __restrict__ Wr0,
    const float* __restrict__ Wl1, const float* __restrict__ Wr1,
    const float* __restrict__ Wl2, const float* __restrict__ Wr2,
    const float* __restrict__ Wl3, const float* __restrict__ Wr3,
    ushort_t* __restrict__ wdst,
    const int* __restrict__ src, const int* __restrict__ dst, const int* __restrict__ ld,
    int* __restrict__ bcnt, int E, int L, int nct, int NBt, int NBe) {
  const int b = blockIdx.x;
  const int tid = threadIdx.x;
  if (b < 2048) {
    size_t i = (size_t)b * 256 + tid;
    size_t s = 2048 * 256;
    for (; i < n4tot; i += s) {
      float4 v = (i < n4a) ? ((const float4*)xa)[i] : ((const float4*)xb)[i - n4a];
      uint2 r;
      r.x = pkh(v.x, v.y);
      r.y = pkh(v.z, v.w);
      xout[i] = r;
    }
  } else if (b < 2560) {
    int i = (b - 2048) * 256 + tid;  // 0..131071
    int w = i >> 15;
    int ii = i & 32767;
    int j = ii & 7;
    int lane = (ii >> 3) & 63;
    int nf = (ii >> 9) & 7;
    int ks = ii >> 12;
    int k = ks * 32 + (lane >> 4) * 8 + j;
    int nn = nf * 16 + (lane & 15);
    const float* Wl = (w == 0) ? Wl0 : (w == 1) ? Wl1 : (w == 2) ? Wl2 : Wl3;
    const float* Wr = (w == 0) ? Wr0 : (w == 1) ? Wr1 : (w == 2) ? Wr2 : Wr3;
    float v = (k < H) ? Wl[k * H + nn] : Wr[(k - H) * H + nn];
    wdst[i] = __builtin_bit_cast(ushort_t, (_Float16)v);
  } else {
    // bucket counts (bcnt pre-zeroed by hipMemsetAsync); labels bucketed by TEAM (ld)
    __shared__ int hist[256];
    int cb = b - 2560;
    int stream, i0, n, base, shift;
    if (cb < nct) { stream = 0; i0 = cb * CH; n = E; base = 0; shift = 8; }
    else if (cb < 2 * nct) { stream = 1; i0 = (cb - nct) * CH; n = E; base = NBt; shift = 9; }
    else { stream = 2; i0 = (cb - 2 * nct) * CH; n = L; base = NBt + NBe; shift = 8; }
    const int* idx = (stream == 0) ? dst : (stream == 1) ? src : ld;
    const int i1 = min(n, i0 + CH);
    hist[tid] = 0;
    __syncthreads();
    for (int i = i0 + tid; i < i1; i += 256) atomicAdd(&hist[idx[i] >> shift], 1);
    __syncthreads();
    int h = hist[tid];
    if (h) atomicAdd(&bcnt[base + tid], h);
  }
}

// ---------------------------------------------------------------- tiny bucket scan (1 block)
__global__ void scan_buckets(const int* __restrict__ bcnt, int* __restrict__ boff,
                             int* __restrict__ cur, int n) {
  __shared__ int s[256];
  const int t = threadIdx.x;
  int carry = 0;
  for (int base = 0; base < n; base += 256) {
    int i = base + t;
    int v = (i < n) ? bcnt[i] : 0;
    s[t] = v;
    __syncthreads();
    for (int off = 1; off < 256; off <<= 1) {
      int x = (t >= off) ? s[t - off] : 0;
      __syncthreads();
      s[t] += x;
      __syncthreads();
    }
    if (i < n) { boff[i] = s[t] - v + carry; cur[i] = s[t] - v + carry; }
    __syncthreads();
    carry += s[255];
    __syncthreads();
  }
  if (t == 0) boff[n] = carry;
}

// ---------------------------------------------------------------- pass 1: radix bucket scatter
__global__ __launch_bounds__(256) void bucket_scatter(
    const int* __restrict__ src, const int* __restrict__ dst,
    const int* __restrict__ ls, const int* __restrict__ ld,
    int* __restrict__ cur, u64_t* __restrict__ recs,
    int E, int L, int nct, int NBt, int NBe) {
  __shared__ int hist[256];
  __shared__ int start[256];
  const int b = blockIdx.x;
  const int tid = threadIdx.x;
  int stream, i0, n, base;
  if (b < nct) { stream = 0; i0 = b * CH; n = E; base = 0; }
  else if (b < 2 * nct) { stream = 1; i0 = (b - nct) * CH; n = E; base = NBt; }
  else { stream = 2; i0 = (b - 2 * nct) * CH; n = L; base = NBt + NBe; }
  const int i1 = min(n, i0 + CH);

  hist[tid] = 0;
  __syncthreads();
  for (int i = i0 + tid; i < i1; i += 256) {
    int d = (stream == 0) ? dst[i] : (stream == 1) ? src[i] : ld[i];
    int bkt = (stream == 1) ? (d >> 9) : (d >> 8);
    atomicAdd(&hist[bkt], 1);
  }
  __syncthreads();
  int h = hist[tid];
  if (h) start[tid] = atomicAdd(&cur[base + tid], h);
  __syncthreads();
  for (int i = i0 + tid; i < i1; i += 256) {
    u64_t rec;
    int bkt;
    if (stream == 0) {
      int d = dst[i];
      rec = ((u64_t)d << 32) | (uint_t)src[i];
      bkt = d >> 8;
    } else if (stream == 1) {
      int d = src[i];
      rec = ((u64_t)d << 32) | (uint_t)dst[i];
      bkt = d >> 9;
    } else {
      int d = ld[i];
      rec = ((u64_t)d << 40) | ((u64_t)(uint_t)ls[i] << 20) | (uint_t)i;  // d:24|ls:20|i:20
      bkt = d >> 8;
    }
    int pos = start[bkt] + atomicSub(&hist[bkt], 1) - 1;
    recs[pos] = rec;
  }
}

// ---------------------------------------------------------------- pass 2: in-bucket place
__global__ __launch_bounds__(256) void place_all(
    const u64_t* __restrict__ recs, const int* __restrict__ boff,
    int* __restrict__ off_t, int* __restrict__ off_e, int* __restrict__ off_l,
    int* __restrict__ adj_t, int* __restrict__ adj_e_m, long long* __restrict__ lpair_m,
    int n_t, int n_e, int NBt, int NBe, int NBl) {
  __shared__ int sh[512];   // counts -> cursors
  __shared__ int tmp[256];
  const int b = blockIdx.x;
  const int tid = threadIdx.x;
  int stream, d0, d1, nmax;
  int* offg;
  if (b < NBt) { stream = 0; d0 = b << 8; d1 = min(n_t, d0 + 256); offg = off_t; nmax = n_t; }
  else if (b < NBt + NBe) { stream = 1; d0 = (b - NBt) << 9; d1 = min(n_e, d0 + 512); offg = off_e; nmax = n_e; }
  else { stream = 2; d0 = (b - NBt - NBe) << 8; d1 = min(n_t, d0 + 256); offg = off_l; nmax = n_t; }
  const int nn = d1 - d0;
  const int rs = boff[b], re = boff[b + 1];

  sh[tid] = 0;
  sh[tid + 256] = 0;
  __syncthreads();
  for (int i = rs + tid; i < re; i += 256) {
    u64_t rec = recs[i];
    int d = (stream == 2) ? (int)(rec >> 40) : (int)(rec >> 32);
    atomicAdd(&sh[d - d0], 1);
  }
  __syncthreads();
  int carry = 0;
  for (int c = 0; c < 2; ++c) {
    int idx = c * 256 + tid;
    int v = sh[idx];
    tmp[tid] = v;
    __syncthreads();
    for (int o = 1; o < 256; o <<= 1) {
      int x = (tid >= o) ? tmp[tid - o] : 0;
      __syncthreads();
      tmp[tid] += x;
      __syncthreads();
    }
    int excl = tmp[tid] - v + carry;
    if (idx < nn) {
      offg[d0 + idx] = rs + excl;
      sh[idx] = rs + excl;  // cursor
    }
    __syncthreads();
    carry += tmp[255];
    __syncthreads();
  }
  if (tid == 0) {
    bool last = (stream == 0 && b == NBt - 1) ||
                (stream == 1 && b == NBt + NBe - 1) ||
                (stream == 2 && b == NBt + NBe + NBl - 1);
    if (last) offg[nmax] = re;
  }
  __syncthreads();
  if (stream == 0) {
    for (int i = rs + tid; i < re; i += 256) {
      u64_t rec = recs[i];
      int d = (int)(rec >> 32);
      adj_t[atomicAdd(&sh[d - d0], 1)] = (int)rec;
    }
  } else if (stream == 1) {
    for (int i = rs + tid; i < re; i += 256) {
      u64_t rec = recs[i];
      int d = (int)(rec >> 32);
      adj_e_m[atomicAdd(&sh[d - d0], 1)] = (int)rec;
    }
  } else {
    for (int i = rs + tid; i < re; i += 256) {
      u64_t rec = recs[i];
      int d = (int)(rec >> 40);
      int lsv = (int)((rec >> 20) & 0xFFFFF);
      int li = (int)(rec & 0xFFFFF);
      lpair_m[atomicAdd(&sh[d - d0], 1)] = ((long long)lsv << 32) | (uint_t)li;
    }
  }
}

// ---------------------------------------------------------------- dual pull mean (slot-per-node, unroll-4)
// wave = 4 independent nodes; each 16-lane slot walks its node's adjacency with
// 4 row-gathers in flight (16/wave).
__global__ void pull_mean_dual(
    const ushort_t* __restrict__ featA, const int* __restrict__ offA, const int* __restrict__ adjA,
    ushort_t* __restrict__ outA, int nA,
    const ushort_t* __restrict__ featB, const int* __restrict__ offB, const int* __restrict__ adjB,
    ushort_t* __restrict__ outB, int nB) {
  int gid = blockIdx.x * blockDim.x + threadIdx.x;
  int wave = gid >> 6;
  int lane = gid & 63;
  int slot = lane >> 4;
  int sl = lane & 15;
  int nw = (gridDim.x * blockDim.x) >> 6;
  const int N = nA + nB;
  for (int v0 = wave * 4; v0 < N; v0 += nw * 4) {
    int v = v0 + slot;
    bool valid = v < N;
    const uint4* f;
    const int* off;
    const int* adj;
    uint4* o;
    int vv;
    if (v < nA) {
      f = (const uint4*)featA; off = offA; adj = adjA; o = (uint4*)outA; vv = v;
    } else {
      f = (const uint4*)featB; off = offB; adj = adjB; o = (uint4*)outB;
      vv = valid ? v - nA : 0;
    }
    int s = 0, e = 0;
    if (valid) { s = off[vv]; e = off[vv + 1]; }
    float acc[8];
#pragma unroll
    for (int c = 0; c < 8; ++c) acc[c] = 0.f;
    int i = s;
    // 4 rows in flight per slot
    for (; i + 4 <= e; i += 4) {
      int i0 = adj[i], i1 = adj[i + 1], i2 = adj[i + 2], i3 = adj[i + 3];
      uint4 u0 = f[(size_t)i0 * 16 + sl];
      uint4 u1 = f[(size_t)i1 * 16 + sl];
      uint4 u2 = f[(size_t)i2 * 16 + sl];
      uint4 u3 = f[(size_t)i3 * 16 + sl];
      acc[0] = dot2(u0.x, LO1, acc[0]); acc[1] = dot2(u0.x, HI1, acc[1]);
      acc[2] = dot2(u0.y, LO1, acc[2]); acc[3] = dot2(u0.y, HI1, acc[3]);
      acc[4] = dot2(u0.z, LO1, acc[4]); acc[5] = dot2(u0.z, HI1, acc[5]);
      acc[6] = dot2(u0.w, LO1, acc[6]); acc[7] = dot2(u0.w, HI1, acc[7]);
      acc[0] = dot2(u1.x, LO1, acc[0]); acc[1] = dot2(u1.x, HI1, acc[1]);
      acc[2] = dot2(u1.y, LO1, acc[2]); acc[3] = dot2(u1.y, HI1, acc[3]);
      acc[4] = dot2(u1.z, LO1, acc[4]); acc[5] = dot2(u1.z, HI1, acc[5]);
      acc[6] = dot2(u1.w, LO1, acc[6]); acc[7] = dot2(u1.w, HI1, acc[7]);
      acc[0] = dot2(u2.x, LO1, acc[0]); acc[1] = dot2(u2.x, HI1, acc[1]);
      acc[2] = dot2(u2.y, LO1, acc[2]); acc[3] = dot2(u2.y, HI1, acc[3]);
      acc[4] = dot2(u2.z, LO1, acc[4]); acc[5] = dot2(u2.z, HI1, acc[5]);
      acc[6] = dot2(u2.w, LO1, acc[6]); acc[7] = dot2(u2.w, HI1, acc[7]);
      acc[0] = dot2(u3.x, LO1, acc[0]); acc[1] = dot2(u3.x, HI1, acc[1]);
      acc[2] = dot2(u3.y, LO1, acc[2]); acc[3] = dot2(u3.y, HI1, acc[3]);
      acc[4] = dot2(u3.z, LO1, acc[4]); acc[5] = dot2(u3.z, HI1, acc[5]);
      acc[6] = dot2(u3.w, LO1, acc[6]); acc[7] = dot2(u3.w, HI1, acc[7]);
    }
    for (; i + 2 <= e; i += 2) {
      int i0 = adj[i], i1 = adj[i + 1];
      uint4 u0 = f[(size_t)i0 * 16 + sl];
      uint4 u1 = f[(size_t)i1 * 16 + sl];
      acc[0] = dot2(u0.x, LO1, acc[0]); acc[1] = dot2(u0.x, HI1, acc[1]);
      acc[2] = dot2(u0.y, LO1, acc[2]); acc[3] = dot2(u0.y, HI1, acc[3]);
      acc[4] = dot2(u0.z, LO1, acc[4]); acc[5] = dot2(u0.z, HI1, acc[5]);
      acc[6] = dot2(u0.w, LO1, acc[6]); acc[7] = dot2(u0.w, HI1, acc[7]);
      acc[0] = dot2(u1.x, LO1, acc[0]); acc[1] = dot2(u1.x, HI1, acc[1]);
      acc[2] = dot2(u1.y, LO1, acc[2]); acc[3] = dot2(u1.y, HI1, acc[3]);
      acc[4] = dot2(u1.z, LO1, acc[4]); acc[5] = dot2(u1.z, HI1, acc[5]);
      acc[6] = dot2(u1.w, LO1, acc[6]); acc[7] = dot2(u1.w, HI1, acc[7]);
    }
    if (i < e) {
      uint4 u = f[(size_t)adj[i] * 16 + sl];
      acc[0] = dot2(u.x, LO1, acc[0]); acc[1] = dot2(u.x, HI1, acc[1]);
      acc[2] = dot2(u.y, LO1, acc[2]); acc[3] = dot2(u.y, HI1, acc[3]);
      acc[4] = dot2(u.z, LO1, acc[4]); acc[5] = dot2(u.z, HI1, acc[5]);
      acc[6] = dot2(u.w, LO1, acc[6]); acc[7] = dot2(u.w, HI1, acc[7]);
    }
    if (valid) {
      float rd = 1.0f / fmaxf((float)(e - s), 1.0f);
      uint4 ov;
      ov.x = pkh(acc[0] * rd, acc[1] * rd);
      ov.y = pkh(acc[2] * rd, acc[3] * rd);
      ov.z = pkh(acc[4] * rd, acc[5] * rd);
      ov.w = pkh(acc[6] * rd, acc[7] * rd);
      o[(size_t)vv * 16 + sl] = ov;
    }
  }
}

// ---------------------------------------------------------------- dual MFMA GEMM (f16)
// (256,2): keeps B[8][4] (128 VGPR) register-resident (round-10 regression lesson)
template <bool RELU>
__global__ __launch_bounds__(256, 2) void gemm_mfma_dual(
    const ushort_t* __restrict__ aggA, const ushort_t* __restrict__ xdA,
    const ushort_t* __restrict__ wfA, const float* __restrict__ biasA,
    ushort_t* __restrict__ outA, int nA, int gA,
    const ushort_t* __restrict__ aggB, const ushort_t* __restrict__ xdB,
    const ushort_t* __restrict__ wfB, const float* __restrict__ biasB,
    ushort_t* __restrict__ outB, int nB) {
  __shared__ __align__(16) ushort_t sA[64 * 128];
  __shared__ __align__(16) ushort_t sX[64 * 128];
  const ushort_t *agg, *xd, *wfrag;
  const float* bias;
  ushort_t* outp;
  int n, b0, nbl;
  if ((int)blockIdx.x < gA) {
    agg = aggA; xd = xdA; wfrag = wfA; bias = biasA; outp = outA; n = nA;
    b0 = blockIdx.x; nbl = gA;
  } else {
    agg = aggB; xd = xdB; wfrag = wfB; bias = biasB; outp = outB; n = nB;
    b0 = blockIdx.x - gA; nbl = gridDim.x - gA;
  }
  const int t = threadIdx.x;
  const int lane = t & 63;
  const int wid = t >> 6;
  const int mrow = (wid >> 1) * 32;
  const int nhalf = (wid & 1) * 64;

  s16x8 B[8][4];
#pragma unroll
  for (int ks = 0; ks < 8; ++ks)
#pragma unroll
    for (int nfi = 0; nfi < 4; ++nfi)
      B[ks][nfi] = *(const s16x8*)(wfrag + (size_t)(((ks << 3) | ((nhalf >> 4) + nfi)) << 9) + (lane << 3));

  float bv[4];
#pragma unroll
  for (int nfi = 0; nfi < 4; ++nfi) bv[nfi] = bias[nhalf + nfi * 16 + (lane & 15)];

  const int lrow = lane >> 4;
  const int pbyte = (lane & 15) << 4;

  const int ntiles = (n + 63) >> 6;
  for (int tile = b0; tile < ntiles; tile += nbl) {
    const int row0 = tile << 6;
#pragma unroll
    for (int i = 0; i < 8; ++i) {
      int reg = (wid << 3) + i;
      int rr = ((reg & 15) << 2) + lrow;
      int row = row0 + rr;
      row = row < n ? row : n - 1;
      int pp = pbyte ^ ((rr & 7) << 4);
      const ushort_t* srcp = (reg < 16 ? agg : xd) + (size_t)row * H + (pp >> 1);
      ushort_t* ldst = (reg < 16 ? sA : sX) + ((reg & 15) << 9);
      gload_lds16(srcp, ldst);
    }
    __syncthreads();

    f32x4 acc[2][4];
#pragma unroll
    for (int mi = 0; mi < 2; ++mi)
#pragma unroll
      for (int nfi = 0; nfi < 4; ++nfi) {
        f32x4 c = {bv[nfi], bv[nfi], bv[nfi], bv[nfi]};
        acc[mi][nfi] = c;
      }

    const int rr0 = mrow + (lane & 15);
    const int rr1 = rr0 + 16;
    const int kx = (lane >> 4) << 4;
    const int sw = (rr0 & 7) << 4;
#pragma unroll
    for (int ks = 0; ks < 8; ++ks) {
      const ushort_t* base = (ks < 4) ? sA : sX;
      const int kb = (ks & 3) << 6;
      s16x8 a0 = *(const s16x8*)((const char*)base + rr0 * 256 + ((kb | kx) ^ sw));
      s16x8 a1 = *(const s16x8*)((const char*)base + rr1 * 256 + ((kb | kx) ^ sw));
#pragma unroll
      for (int nfi = 0; nfi < 4; ++nfi) {
        acc[0][nfi] = __builtin_amdgcn_mfma_f32_16x16x32_f16(a0, B[ks][nfi], acc[0][nfi], 0, 0, 0);
        acc[1][nfi] = __builtin_amdgcn_mfma_f32_16x16x32_f16(a1, B[ks][nfi], acc[1][nfi], 0, 0, 0);
      }
    }

#pragma unroll
    for (int mi = 0; mi < 2; ++mi) {
      int rbase = row0 + mrow + mi * 16 + ((lane >> 4) << 2);
#pragma unroll
      for (int r = 0; r < 4; ++r) {
        int row = rbase + r;
        if (row < n) {
#pragma unroll
          for (int nfi = 0; nfi < 4; ++nfi) {
            float v = acc[mi][nfi][r];
            if (RELU) v = fmaxf(v, 0.f);
            outp[(size_t)row * H + nhalf + nfi * 16 + (lane & 15)] =
                __builtin_bit_cast(ushort_t, (_Float16)v);
          }
        }
      }
    }
    __syncthreads();
  }
}

// ---------------------------------------------------------------- grouped edge dot (by team)
__global__ void edge_dot_grouped(const ushort_t* __restrict__ ze, const ushort_t* __restrict__ zt,
                                 const int* __restrict__ loff, const long long* __restrict__ lpair,
                                 float* __restrict__ out, int n_t) {
  int gid = blockIdx.x * blockDim.x + threadIdx.x;
  int wave = gid >> 6;
  int lane = gid & 63;
  int slot = lane >> 4;
  int sl = lane & 15;
  int nw = (gridDim.x * blockDim.x) >> 6;
  const uint4* fz = (const uint4*)ze;
  const uint4* ft = (const uint4*)zt;
  for (int v = wave; v < n_t; v += nw) {
    int s = loff[v], e = loff[v + 1];
    if (s == e) continue;
    uint4 b = ft[(size_t)v * 16 + sl];
    for (int i = s; i < e; i += 4) {
      int j = i + slot;
      bool val = j < e;
      long long q = lpair[val ? j : i];
      int row = (int)(q >> 32);
      uint4 u = fz[(size_t)row * 16 + sl];
      float p = dot2(u.x, b.x, dot2(u.y, b.y, dot2(u.z, b.z, dot2(u.w, b.w, 0.f))));
      p += __shfl_xor(p, 1);
      p += __shfl_xor(p, 2);
      p += __shfl_xor(p, 4);
      p += __shfl_xor(p, 8);
      if (sl == 0 && val) __builtin_nontemporal_store(p, &out[(int)q]);
    }
  }
}

// ---------------------------------------------------------------- launch
extern "C" void kernel_launch(void* const* d_in, const int* in_sizes, int n_in,
                              void* d_out, int out_size, void* d_ws, size_t ws_size,
                              hipStream_t stream) {
  const float* x_e = (const float*)d_in[0];
  const float* x_t = (const float*)d_in[1];
  const int* src = (const int*)d_in[2];
  const int* dst = (const int*)d_in[3];
  const int* ls = (const int*)d_in[4];
  const int* ld = (const int*)d_in[5];
  const float* W1et_l = (const float*)d_in[6];
  const float* W1et_r = (const float*)d_in[7];
  const float* W1te_l = (const float*)d_in[8];
  const float* W1te_r = (const float*)d_in[9];
  const float* W2et_l = (const float*)d_in[10];
  const float* W2et_r = (const float*)d_in[11];
  const float* W2te_l = (const float*)d_in[12];
  const float* W2te_r = (const float*)d_in[13];
  const float* b1et = (const float*)d_in[14];
  const float* b1te = (const float*)d_in[15];
  const float* b2et = (const float*)d_in[16];
  const float* b2te = (const float*)d_in[17];

  const int n_e = in_sizes[0] / H;
  const int n_t = in_sizes[1] / H;
  const int E = in_sizes[2];
  const int L = in_sizes[4];
  float* out = (float*)d_out;

  const size_t fe = (size_t)n_e * H;
  const size_t ft = (size_t)n_t * H;
  ushort_t* us = (ushort_t*)d_ws;
  ushort_t* xb_e = us;               // fe
  ushort_t* xb_t = xb_e + fe;        // ft
  ushort_t* agg_e = xb_t + ft;       // fe  (layer2: z_expert in place)
  ushort_t* agg_t = agg_e + fe;      // ft  (… z_team in place)
  ushort_t* h_e = agg_t + ft;        // fe
  ushort_t* h_t = h_e + fe;          // ft
  ushort_t* wfrag = h_t + ft;        // 4*32768
  int* ib = (int*)(wfrag + 4 * 32768);

  const int Mt = n_t + 1, Me = n_e + 1, Ml = n_t + 1;
  const int NBt = (n_t + 255) >> 8;   // team buckets (256)
  const int NBe = (n_e + 511) >> 9;   // expert buckets (512)
  const int NBl = NBt;                // labels bucketed by team
  const int NBtot = NBt + NBe + NBl;

  int* off = ib;                   // Mt+Me+Ml  ([off_t | off_e(+E) | off_l(+2E)])
  int* bcnt = off + Mt + Me + Ml;  // NBtot+1
  int* boff = bcnt + NBtot + 1;    // NBtot+1
  int* cur = boff + NBtot + 1;     // NBtot
  int* adj_t = cur + NBtot;        // E
  int* adj_e = adj_t + E;          // E
  long long* lpair = (long long*)(((unsigned long long)(adj_e + E) + 7) & ~7ULL);  // L
  u64_t* recs = (u64_t*)(lpair + L);  // 2E+L

  int* off_t = off;
  int* off_e = off + Mt;            // values in [E, 2E]
  int* off_l = off + Mt + Me;       // values in [2E, 2E+L]
  int* adj_e_m = adj_e - E;
  long long* lpair_m = lpair - 2 * (size_t)E;

  const int nct = (E + CH - 1) / CH;
  const int ncl = (L + CH - 1) / CH;
  const int nbc = 2 * nct + ncl;

  const dim3 blk(256);

  // ---- zero bucket counters, then merged prologue (cvt + wfrag + bucket counts)
  hipMemsetAsync(bcnt, 0, (size_t)(NBtot + 1) * 4, stream);
  prep_kernel<<<2560 + nbc, blk, 0, stream>>>(
      x_e, x_t, fe / 4, (fe + ft) / 4, (uint2*)xb_e,
      W1et_l, W1et_r, W1te_l, W1te_r, W2et_l, W2et_r, W2te_l, W2te_r, wfrag,
      src, dst, ld, bcnt, E, L, nct, NBt, NBe);

  // ---- CSR build: tiny scan -> radix scatter -> in-bucket place
  scan_buckets<<<1, blk, 0, stream>>>(bcnt, boff, cur, NBtot);
  bucket_scatter<<<nbc, blk, 0, stream>>>(src, dst, ls, ld, cur, recs, E, L, nct, NBt, NBe);
  place_all<<<NBtot, blk, 0, stream>>>(recs, boff, off_t, off_e, off_l,
                                       adj_t, adj_e_m, lpair_m, n_t, n_e, NBt, NBe, NBl);

  const int gt = (n_t + 63) / 64, ge = (n_e + 63) / 64;
  const int gA = min(gt, 512), gB = min(ge, 512);
  const int npull = ((n_t + n_e) + 3) / 4;

  // ---- layer 1
  pull_mean_dual<<<npull, blk, 0, stream>>>(xb_e, off_t, adj_t, agg_t, n_t,
                                            xb_t, off_e, adj_e_m, agg_e, n_e);
  gemm_mfma_dual<true><<<gA + gB, blk, 0, stream>>>(
      agg_t, xb_t, wfrag + 0 * 32768, b1et, h_t, n_t, gA,
      agg_e, xb_e, wfrag + 1 * 32768, b1te, h_e, n_e);

  // ---- layer 2 (z written in place over agg)
  pull_mean_dual<<<npull, blk, 0, stream>>>(h_e, off_t, adj_t, agg_t, n_t,
                                            h_t, off_e, adj_e_m, agg_e, n_e);
  gemm_mfma_dual<false><<<gA + gB, blk, 0, stream>>>(
      agg_t, h_t, wfrag + 2 * 32768, b2et, agg_t, n_t, gA,
      agg_e, h_e, wfrag + 3 * 32768, b2te, agg_e, n_e);

  // ---- grouped edge dot readout (held = z_team, gathered = z_expert)
  edge_dot_grouped<<<(n_t + 3) / 4, blk, 0, stream>>>(agg_e, agg_t, off_l, lpair_m, out, n_t);
}